// Round 5
// baseline (308.067 us; speedup 1.0000x reference)
//
#include <hip/hip_runtime.h>
#include <hip/hip_bf16.h>

using bf16 = __hip_bfloat16;

#define DI __device__ __forceinline__

typedef __attribute__((ext_vector_type(8))) short short8;
typedef __attribute__((ext_vector_type(8))) unsigned short u16x8;
typedef __attribute__((ext_vector_type(4))) unsigned short u16x4;
typedef __attribute__((ext_vector_type(4))) float f32x4;

#define MFMA_BF16 __builtin_amdgcn_mfma_f32_16x16x32_bf16

DI float leaky(float x) { return x > 0.f ? x : 0.1f * x; }

// bf16 split helpers (RNE). x = hi + lo to ~2^-16 relative.
DI unsigned short b16(float x) {
  union { float f; unsigned u; } v; v.f = x;
  unsigned r = v.u + 0x7FFFu + ((v.u >> 16) & 1u);
  return (unsigned short)(r >> 16);
}
DI float fromb16(unsigned short h) {
  union { unsigned u; float f; } v; v.u = ((unsigned)h) << 16; return v.f;
}

// Problem constants: B=2, C=64, H=64, W=64, N=4096. Inputs fp32 (R3/R4).
// NOTE R13: hipLaunchCooperativeKernel fails silently under graph capture here.
// Precision ladder (validated): Q/K split bf16, P hi-only, V hi-only in PV,
// L via ones-row MFMA. R2: swapped QK^T -> lane owns one pixel.
// R4: convs channel-split (block = 1 row x 4 oc, 4 waves x 16 ch, upfront loads).
// R5: attn was GRID-limited at 2 blocks/CU (8 waves/CU). Now 512 thr/block:
// waves 0-3 and 4-7 split this half's 32 K-tiles 16/16 on separate LDS
// K-dbufs, merge (O,M,L) in-block via LDS; V read straight from global
// (V^T contiguous in A-frag order, L2-hit, hidden under QK) -> LDS 80KB,
// 2 blocks/CU = 16 waves/CU. P-writes packed to 8B stores (was 16 scalar
// b16 stores/tile -> 1.05M bank-conflict cycles in R4 counters).
static constexpr int N_ = 4096;
static constexpr size_t CN = 262144;
static constexpr size_t BCN = 524288;

// ---- Workspace layout (float indices) ----
static constexpr size_t XG_OFF = 137104;
static constexpr size_t GG_OFF = XG_OFF + BCN;
static constexpr size_t QX_OFF = GG_OFF + BCN;
static constexpr size_t KX_OFF = QX_OFF + BCN;
static constexpr size_t VX_OFF = KX_OFF + BCN;
static constexpr size_t QG_OFF = VX_OFF + BCN;
static constexpr size_t KG_OFF = QG_OFF + BCN;
static constexpr size_t P1X_OFF = KG_OFF + BCN;
static constexpr size_t P1G_OFF = P1X_OFF + BCN;
static constexpr size_t ML_OFF  = P1G_OFF + BCN;
static constexpr size_t MLL_OFF = ML_OFF + 32768;
static constexpr size_t CA_OFF = ML_OFF;   // 256 floats; consumed by coordconv before attn writes ML
static constexpr size_t OB_OFF = QX_OFF;
static constexpr size_t UB_OFF = KX_OFF;
static constexpr size_t GO_OFF = GG_OFF;
static constexpr size_t QXH_U = QX_OFF * 2, QXL_U = QXH_U + BCN;
static constexpr size_t KXH_U = KX_OFF * 2, KXL_U = KXH_U + BCN;
static constexpr size_t VXH_U = VX_OFF * 2;
static constexpr size_t QGH_U = QG_OFF * 2, QGL_U = QGH_U + BCN;
static constexpr size_t KGH_U = KG_OFF * 2, KGL_U = KGH_U + BCN;
// Peak 19.7 MB (validated R6-R14)

// ---------------- K0: channel-attention scales (256 = src*128 + b*64 + ch) ----------------
__global__ __launch_bounds__(64) void k_ca(const float* __restrict__ x,
                                           const float* __restrict__ g,
                                           const float* __restrict__ lw_p,
                                           const float* __restrict__ lb_p,
                                           float* __restrict__ ws) {
  int blk = blockIdx.x;
  int ch = blk & 63; blk >>= 6;
  int b  = blk & 1;  blk >>= 1;
  int src = blk;
  const float* in = (src ? g : x) + ((size_t)(b * 64 + ch)) * N_;
  int t = threadIdx.x;
  float s = 0.f;
#pragma unroll
  for (int i = 0; i < 16; ++i) {
    float4 v = *reinterpret_cast<const float4*>(in + i * 256 + t * 4);
    s += (v.x + v.y) + (v.z + v.w);
  }
#pragma unroll
  for (int d = 1; d < 64; d <<= 1) s += __shfl_xor(s, d, 64);
  if (t == 0) {
    float p = s * (1.f / 4096.f);
    float lwv = lw_p[0], lbv = lb_p[0];
    float h = leaky(lwv * p + lbv);
    ws[CA_OFF + (src * 2 + b) * 64 + ch] = 1.f / (1.f + expf(-(lwv * h + lbv)));
  }
}

// ---------------- K1: coord-conv 3x3, channel-split (1 row x 4 oc / block) ----------------
__global__ __launch_bounds__(256) void k_coordconv(const float* __restrict__ x,
                                                   const float* __restrict__ g,
                                                   const float* __restrict__ cw,
                                                   float* __restrict__ ws) {
  int blk = blockIdx.x;  // 4096 = src*2048 + b*1024 + og*64 + row
  int row = blk & 63; blk >>= 6;
  int og  = blk & 15; blk >>= 4;
  int b   = blk & 1;  blk >>= 1;
  int src = blk;
  int o0 = og * 4;
  const float* in = src ? g : x;
  float* outp = ws + (src ? GG_OFF : XG_OFF);
  __shared__ __align__(16) float4 wl4[594];   // [ch*9+tap] -> 4 oc
  __shared__ float part[4][4][64];
  int t = threadIdx.x;
  int wv = t >> 6, px = t & 63;
  {
    float* wlf = (float*)wl4;
    for (int idx = t; idx < 2376; idx += 256)
      wlf[idx] = cw[(size_t)(o0 + (idx & 3)) * 594 + (idx >> 2)];
  }
  int rm = row - 1, rp = row + 1;
  int rmc = rm < 0 ? 0 : rm, rpc = rp > 63 ? 63 : rp;
  float maskm = rm < 0 ? 0.f : 1.f, maskp = rp > 63 ? 0.f : 1.f;
  int c0 = wv * 16;
  const float* base = in + ((size_t)(b * 64 + c0)) * N_ + px;
  float ra[16], rb[16], rc[16];
#pragma unroll
  for (int i = 0; i < 16; ++i) {
    ra[i] = base[(size_t)i * N_ + (size_t)rmc * 64] * maskm;
    rb[i] = base[(size_t)i * N_ + (size_t)row * 64];
    rc[i] = base[(size_t)i * N_ + (size_t)rpc * 64] * maskp;
  }
  float acc[4] = {};
  auto tap9 = [&](int ch, float va, float vb, float vc) {
    float la = __shfl_up(va, 1, 64);   if (px == 0)  la = 0.f;
    float ga = __shfl_down(va, 1, 64); if (px == 63) ga = 0.f;
    float lb = __shfl_up(vb, 1, 64);   if (px == 0)  lb = 0.f;
    float gb = __shfl_down(vb, 1, 64); if (px == 63) gb = 0.f;
    float lc = __shfl_up(vc, 1, 64);   if (px == 0)  lc = 0.f;
    float gc = __shfl_down(vc, 1, 64); if (px == 63) gc = 0.f;
    float4 w0 = wl4[ch * 9 + 0], w1 = wl4[ch * 9 + 1], w2 = wl4[ch * 9 + 2];
    float4 w3 = wl4[ch * 9 + 3], w4 = wl4[ch * 9 + 4], w5 = wl4[ch * 9 + 5];
    float4 w6 = wl4[ch * 9 + 6], w7 = wl4[ch * 9 + 7], w8 = wl4[ch * 9 + 8];
    acc[0] = fmaf(w0.x, la, fmaf(w1.x, va, fmaf(w2.x, ga, acc[0])));
    acc[1] = fmaf(w0.y, la, fmaf(w1.y, va, fmaf(w2.y, ga, acc[1])));
    acc[2] = fmaf(w0.z, la, fmaf(w1.z, va, fmaf(w2.z, ga, acc[2])));
    acc[3] = fmaf(w0.w, la, fmaf(w1.w, va, fmaf(w2.w, ga, acc[3])));
    acc[0] = fmaf(w3.x, lb, fmaf(w4.x, vb, fmaf(w5.x, gb, acc[0])));
    acc[1] = fmaf(w3.y, lb, fmaf(w4.y, vb, fmaf(w5.y, gb, acc[1])));
    acc[2] = fmaf(w3.z, lb, fmaf(w4.z, vb, fmaf(w5.z, gb, acc[2])));
    acc[3] = fmaf(w3.w, lb, fmaf(w4.w, vb, fmaf(w5.w, gb, acc[3])));
    acc[0] = fmaf(w6.x, lc, fmaf(w7.x, vc, fmaf(w8.x, gc, acc[0])));
    acc[1] = fmaf(w6.y, lc, fmaf(w7.y, vc, fmaf(w8.y, gc, acc[1])));
    acc[2] = fmaf(w6.z, lc, fmaf(w7.z, vc, fmaf(w8.z, gc, acc[2])));
    acc[3] = fmaf(w6.w, lc, fmaf(w7.w, vc, fmaf(w8.w, gc, acc[3])));
  };
  __syncthreads();   // weights ready
#pragma unroll
  for (int i = 0; i < 16; ++i) tap9(c0 + i, ra[i], rb[i], rc[i]);
  if (wv == 3) {
    // ch 64: xx varies along px (zero-padded rows/cols like real channels)
    float xx = (float)px * (2.f / 63.f) - 1.f;
    tap9(64, maskm * xx, xx, maskp * xx);
    // ch 65: yy constant along px, varies by row
    float ya = maskm * ((float)rm * (2.f / 63.f) - 1.f);
    float yb = (float)row * (2.f / 63.f) - 1.f;
    float yc = maskp * ((float)rp * (2.f / 63.f) - 1.f);
    tap9(65, ya, yb, yc);
  }
#pragma unroll
  for (int oo = 0; oo < 4; ++oo) part[wv][oo][px] = acc[oo];
  __syncthreads();
  int oc = t >> 6;
  float s = (part[0][oc][px] + part[1][oc][px]) + (part[2][oc][px] + part[3][oc][px]);
  float cav = ws[CA_OFF + (src * 2 + b) * 64 + o0 + oc];
  outp[((size_t)(b * 64 + o0 + oc)) * N_ + (size_t)row * 64 + px] = s * cav;
}

// ---------------- K2: 1x1 projections; Q/K pre-split hi/lo, V hi-only transposed ----------------
__global__ __launch_bounds__(256) void k_proj(float* __restrict__ ws,
                                              const float* __restrict__ xqw, const float* __restrict__ xqb,
                                              const float* __restrict__ xkw, const float* __restrict__ xkb,
                                              const float* __restrict__ xvw, const float* __restrict__ xvb,
                                              const float* __restrict__ gqw, const float* __restrict__ gqb,
                                              const float* __restrict__ gkw, const float* __restrict__ gkb) {
  int blk = blockIdx.x;  // 5 * 2 * 64
  int pt = blk & 63; blk >>= 6;
  int b  = blk & 1;  blk >>= 1;
  int which = blk;
  size_t in_o;
  const float *wp, *bp;
  size_t hU = 0, lU = 0;
  if (which == 0)      { in_o = XG_OFF; wp = xqw; bp = xqb; hU = QXH_U; lU = QXL_U; }
  else if (which == 1) { in_o = XG_OFF; wp = xkw; bp = xkb; hU = KXH_U; lU = KXL_U; }
  else if (which == 2) { in_o = XG_OFF; wp = xvw; bp = xvb; }
  else if (which == 3) { in_o = GG_OFF; wp = gqw; bp = gqb; hU = QGH_U; lU = QGL_U; }
  else                 { in_o = GG_OFF; wp = gkw; bp = gkb; hU = KGH_U; lU = KGL_U; }

  __shared__ float tile[64 * 64];
  __shared__ float wl[64 * 65];
  __shared__ float bl[64];
  unsigned short* us = (unsigned short*)ws;
  int t = threadIdx.x;
  int pb = pt * 64;
  const float* in0 = ws + in_o + (size_t)b * CN + pb;
  for (int c0 = (t >> 6); c0 < 64; c0 += 4)
    tile[c0 * 64 + (t & 63)] = in0[(size_t)c0 * N_ + (t & 63)];
  for (int idx = t; idx < 4096; idx += 256)
    wl[(idx >> 6) * 65 + (idx & 63)] = wp[idx];
  if (t < 64) bl[t] = bp[t];
  __syncthreads();
  int o = t & 63, grp = t >> 6;
  const float* wr = &wl[o * 65];
  float acc[16];
  float bv = bl[o];
#pragma unroll
  for (int j = 0; j < 16; ++j) acc[j] = bv;
  for (int c = 0; c < 64; ++c) {
    float wv = wr[c];
    const float4* tb = reinterpret_cast<const float4*>(&tile[c * 64 + grp * 16]);
    float4 t0 = tb[0], t1 = tb[1], t2 = tb[2], t3 = tb[3];
    acc[0] = fmaf(wv, t0.x, acc[0]);   acc[1] = fmaf(wv, t0.y, acc[1]);
    acc[2] = fmaf(wv, t0.z, acc[2]);   acc[3] = fmaf(wv, t0.w, acc[3]);
    acc[4] = fmaf(wv, t1.x, acc[4]);   acc[5] = fmaf(wv, t1.y, acc[5]);
    acc[6] = fmaf(wv, t1.z, acc[6]);   acc[7] = fmaf(wv, t1.w, acc[7]);
    acc[8] = fmaf(wv, t2.x, acc[8]);   acc[9] = fmaf(wv, t2.y, acc[9]);
    acc[10] = fmaf(wv, t2.z, acc[10]); acc[11] = fmaf(wv, t2.w, acc[11]);
    acc[12] = fmaf(wv, t3.x, acc[12]); acc[13] = fmaf(wv, t3.y, acc[13]);
    acc[14] = fmaf(wv, t3.z, acc[14]); acc[15] = fmaf(wv, t3.w, acc[15]);
  }
  if (which != 2) {
#pragma unroll
    for (int j = 0; j < 16; ++j) {
      size_t idx = ((size_t)b * N_ + pb + grp * 16 + j) * 64 + o;
      unsigned short hi = b16(acc[j]);
      us[hU + idx] = hi;
      us[lU + idx] = b16(acc[j] - fromb16(hi));
    }
  } else {
    __syncthreads();
    float* ot = wl;
#pragma unroll
    for (int j = 0; j < 16; ++j) ot[o * 65 + grp * 16 + j] = acc[j];
    __syncthreads();
    int o2 = t >> 2;
#pragma unroll
    for (int e = 0; e < 4; ++e) {
      int px = (t & 3) * 16 + e * 4;
      u16x4 hv;
#pragma unroll
      for (int q = 0; q < 4; ++q) hv[q] = b16(ot[o2 * 65 + px + q]);
      size_t idx = ((size_t)(b * 64 + o2)) * N_ + pb + px;
      *reinterpret_cast<u16x4*>(&us[VXH_U + idx]) = hv;
    }
  }
}

// ---------------- K3: MFMA flash attention, 8 waves: in-block K-split + merge ----------------
__global__ __launch_bounds__(512, 4) void k_attn(float* __restrict__ ws) {
  unsigned short* us = (unsigned short*)ws;
  int blk = blockIdx.x;
  int half = blk & 1; blk >>= 1;
  int qt = blk & 63;  blk >>= 6;
  int b  = blk & 1;   blk >>= 1;
  int at = blk;
  const unsigned short* QH = us + (at ? QGH_U : QXH_U);
  const unsigned short* QL = us + (at ? QGL_U : QXL_U);
  const unsigned short* KHg = us + (at ? KGH_U : KXH_U);
  const unsigned short* KLg = us + (at ? KGL_U : KXL_U);
  const unsigned short* VHg = us + VXH_U;
  float* Pg = ws + (at ? (half ? P1G_OFF : GG_OFF) : (half ? P1X_OFF : XG_OFF))
            + (size_t)b * CN + qt * 64;

  // per group (g=0,1): Kh dbuf [2][4096] | Kl dbuf [2][4096] | Ph [4096]
  __shared__ __align__(16) unsigned short lds[40960];   // 80 KB total

  int t = threadIdx.x;
  int g = t >> 8, tg = t & 255;
  int w = tg >> 6, lane = tg & 63, quad = lane >> 4, l15 = lane & 15;
  int swz = l15 & 7;
  unsigned short* Kh0 = lds + g * 20480;
  unsigned short* Kl0 = lds + g * 20480 + 8192;
  unsigned short* Phg = lds + g * 20480 + 16384;

  short8 qh[2], ql[2];
  {
    size_t qbase = ((size_t)b * N_ + qt * 64 + 16 * w + l15) * 64;
#pragma unroll
    for (int ks = 0; ks < 2; ++ks) {
      qh[ks] = *reinterpret_cast<const short8*>(&QH[qbase + ks * 32 + quad * 8]);
      ql[ks] = *reinterpret_cast<const short8*>(&QL[qbase + ks * 32 + quad * 8]);
    }
  }

  short8 ones;
#pragma unroll
  for (int j = 0; j < 8; ++j) ones[j] = (short)0x3F80;  // bf16 1.0

  int mt0 = half * 32 + g * 16;   // this group's 16 K-tiles

  u16x8 rkh[2], rkl[2];
  size_t ko = ((size_t)b * N_ + (size_t)mt0 * 64 + (tg >> 3)) * 64 + (size_t)(tg & 7) * 8;
  auto prefetchK = [&]() {
    rkh[0] = *reinterpret_cast<const u16x8*>(&KHg[ko]);
    rkl[0] = *reinterpret_cast<const u16x8*>(&KLg[ko]);
    rkh[1] = *reinterpret_cast<const u16x8*>(&KHg[ko + 2048]);
    rkl[1] = *reinterpret_cast<const u16x8*>(&KLg[ko + 2048]);
    ko += 4096;
  };
  int wr0 = tg >> 3, wch = tg & 7;
  int woff = wr0 * 64 + ((wch ^ (wr0 & 7)) << 3);
  auto writebufK = [&](int par) {
    *reinterpret_cast<u16x8*>(&Kh0[par * 4096 + woff]) = rkh[0];
    *reinterpret_cast<u16x8*>(&Kl0[par * 4096 + woff]) = rkl[0];
    *reinterpret_cast<u16x8*>(&Kh0[par * 4096 + woff + 2048]) = rkh[1];
    *reinterpret_cast<u16x8*>(&Kl0[par * 4096 + woff + 2048]) = rkl[1];
  };

  // V straight from global: lane needs V[ch=cs*16+l15][mt*64 + ks*32 + quad*8 ..+7]
  size_t vb = ((size_t)(b * 64 + l15)) * N_ + (size_t)mt0 * 64 + quad * 8;

  f32x4 Oa[4] = {{0.f, 0.f, 0.f, 0.f}, {0.f, 0.f, 0.f, 0.f},
                 {0.f, 0.f, 0.f, 0.f}, {0.f, 0.f, 0.f, 0.f}};
  f32x4 La = {0.f, 0.f, 0.f, 0.f};   // L via ones-row MFMA (rows identical)
  float M = -1e30f;                  // per-lane: pixel n = 16w + l15 (quad-uniform)

  int phb = (16 * w + l15) * 64;
  int mh = quad >> 1, mlw = (quad & 1) * 4;

  prefetchK();
  writebufK(0);
  __syncthreads();
  for (int it = 0; it < 16; ++it) {
    int pb = it & 1;
    // V loads for THIS tile: 8 x 16B, retire under the QK phase
    u16x8 rv[8];
#pragma unroll
    for (int cs = 0; cs < 4; ++cs)
#pragma unroll
      for (int ks = 0; ks < 2; ++ks)
        rv[cs * 2 + ks] = *reinterpret_cast<const u16x8*>(&VHg[vb + (size_t)cs * 16 * N_ + ks * 32]);
    vb += 64;
    if (it + 1 < 16) prefetchK();

    // S^T[m][n]: m = ms*16 + quad*4 + reg, n = 16w + l15 (swapped operands)
    f32x4 S[4];
    __builtin_amdgcn_s_setprio(1);
#pragma unroll
    for (int ms = 0; ms < 4; ++ms) {
      f32x4 a0 = {0.f, 0.f, 0.f, 0.f}, a1 = {0.f, 0.f, 0.f, 0.f};
      int row = ms * 16 + l15;
#pragma unroll
      for (int ks = 0; ks < 2; ++ks) {
        int off = pb * 4096 + row * 64 + (((ks * 4 + quad) ^ swz) << 3);
        short8 khf = *reinterpret_cast<const short8*>(&Kh0[off]);
        short8 klf = *reinterpret_cast<const short8*>(&Kl0[off]);
        f32x4& a = ks ? a1 : a0;
        a = MFMA_BF16(khf, ql[ks], a, 0, 0, 0);
        a = MFMA_BF16(klf, qh[ks], a, 0, 0, 0);
        a = MFMA_BF16(khf, qh[ks], a, 0, 0, 0);
      }
      S[ms] = a0 + a1;
    }
    __builtin_amdgcn_s_setprio(0);

    // in-lane max (max3-shaped) + 2-step cross-quad butterfly
    float t0 = fmaxf(fmaxf(S[0][0], S[0][1]), S[0][2]);
    float t1 = fmaxf(fmaxf(S[0][3], S[1][0]), S[1][1]);
    float t2 = fmaxf(fmaxf(S[1][2], S[1][3]), S[2][0]);
    float t3 = fmaxf(fmaxf(S[2][1], S[2][2]), S[2][3]);
    float t4 = fmaxf(fmaxf(S[3][0], S[3][1]), S[3][2]);
    float t5 = fmaxf(fmaxf(t0, t1), t2);
    float t6 = fmaxf(fmaxf(t3, t4), S[3][3]);
    float tm = fmaxf(t5, t6);
    tm = fmaxf(tm, __shfl_xor(tm, 16, 64));
    tm = fmaxf(tm, __shfl_xor(tm, 32, 64));
    float mn = fmaxf(M, tm);
    float al = __expf(M - mn);
    M = mn;
#pragma unroll
    for (int ms = 0; ms < 4; ++ms) {
      int goff = phb + ((((ms << 1) + mh) ^ swz) << 3) + mlw;
      unsigned lo = (unsigned)b16(__expf(S[ms][0] - mn)) |
                    ((unsigned)b16(__expf(S[ms][1] - mn)) << 16);
      unsigned hi = (unsigned)b16(__expf(S[ms][2] - mn)) |
                    ((unsigned)b16(__expf(S[ms][3] - mn)) << 16);
      uint2 pk; pk.x = lo; pk.y = hi;
      *reinterpret_cast<uint2*>(&Phg[goff]) = pk;   // 8B store, wave-private rows
    }
#pragma unroll
    for (int cs = 0; cs < 4; ++cs) {
      Oa[cs][0] *= al; Oa[cs][1] *= al; Oa[cs][2] *= al; Oa[cs][3] *= al;
    }
    La[0] *= al;

    // O^T += V^T P^T (V from regs): 10 MFMAs incl. 2 ones-row for L
    __builtin_amdgcn_s_setprio(1);
#pragma unroll
    for (int ks = 0; ks < 2; ++ks) {
      int poff = phb + (((ks * 4 + quad) ^ swz) << 3);
      short8 phf = *reinterpret_cast<const short8*>(&Phg[poff]);
      La = MFMA_BF16(ones, phf, La, 0, 0, 0);
#pragma unroll
      for (int cs = 0; cs < 4; ++cs) {
        short8 vhf = (short8)rv[cs * 2 + ks];
        Oa[cs] = MFMA_BF16(vhf, phf, Oa[cs], 0, 0, 0);
      }
    }
    __builtin_amdgcn_s_setprio(0);

    if (it + 1 < 16) writebufK(pb ^ 1);  // fenced by previous iteration's barrier
    __syncthreads();
  }

  // ---- in-block merge of the two 16-tile groups ----
  float* exch = (float*)(lds + 20480);   // group 1's K region (done with it)
  float Lv = La[0];
  if (g == 1) {
#pragma unroll
    for (int cs = 0; cs < 4; ++cs)
#pragma unroll
      for (int r = 0; r < 4; ++r) exch[tg * 16 + cs * 4 + r] = Oa[cs][r];
    if (quad == 0) {
      exch[4096 + 16 * w + l15] = M;
      exch[4160 + 16 * w + l15] = Lv;
    }
  }
  __syncthreads();
  if (g == 0) {
    int n = 16 * w + l15;
    float MB = exch[4096 + n], LB = exch[4160 + n];
    float Mm = fmaxf(M, MB);
    float wA = __expf(M - Mm), wB = __expf(MB - Mm);
    float Lm = Lv * wA + LB * wB;
#pragma unroll
    for (int cs = 0; cs < 4; ++cs) {
#pragma unroll
      for (int r = 0; r < 4; ++r) {
        float o = Oa[cs][r] * wA + exch[tg * 16 + cs * 4 + r] * wB;
        int c = cs * 16 + quad * 4 + r;
        Pg[(size_t)c * N_ + n] = o;
      }
    }
    if (quad == 0) {
      int mlb = ((at * 2 + half) * 2 + b) * 4096 + qt * 64 + n;
      ws[ML_OFF + mlb] = Mm;
      ws[MLL_OFF + mlb] = Lm;
    }
  }
}

// ---------------- K4: merge halves + combine ----------------
__global__ __launch_bounds__(256) void k_merge(float* __restrict__ ws,
                                               const float* __restrict__ gm_p,
                                               const float* __restrict__ al_p) {
  size_t i4 = (size_t)blockIdx.x * 256 + threadIdx.x;
  size_t i = i4 * 4;
  int n = (int)(i & 4095);
  int b = (int)(i >> 18);
  float gm = gm_p[0], al = al_p[0];
  float4 p0x = *reinterpret_cast<const float4*>(ws + XG_OFF + i);
  float4 p1x = *reinterpret_cast<const float4*>(ws + P1X_OFF + i);
  float4 p0g = *reinterpret_cast<const float4*>(ws + GG_OFF + i);
  float4 p1g = *reinterpret_cast<const float4*>(ws + P1G_OFF + i);
  float4 M0x = *reinterpret_cast<const float4*>(ws + ML_OFF  + (0 + b) * 4096 + n);
  float4 L0x = *reinterpret_cast<const float4*>(ws + MLL_OFF + (0 + b) * 4096 + n);
  float4 M1x = *reinterpret_cast<const float4*>(ws + ML_OFF  + (2 + b) * 4096 + n);
  float4 L1x = *reinterpret_cast<const float4*>(ws + MLL_OFF + (2 + b) * 4096 + n);
  float4 M0g = *reinterpret_cast<const float4*>(ws + ML_OFF  + (4 + b) * 4096 + n);
  float4 L0g = *reinterpret_cast<const float4*>(ws + MLL_OFF + (4 + b) * 4096 + n);
  float4 M1g = *reinterpret_cast<const float4*>(ws + ML_OFF  + (6 + b) * 4096 + n);
  float4 L1g = *reinterpret_cast<const float4*>(ws + MLL_OFF + (6 + b) * 4096 + n);
  const float* p0xv = (const float*)&p0x; const float* p1xv = (const float*)&p1x;
  const float* p0gv = (const float*)&p0g; const float* p1gv = (const float*)&p1g;
  const float* m0xv = (const float*)&M0x; const float* l0xv = (const float*)&L0x;
  const float* m1xv = (const float*)&M1x; const float* l1xv = (const float*)&L1x;
  const float* m0gv = (const float*)&M0g; const float* l0gv = (const float*)&L0g;
  const float* m1gv = (const float*)&M1g; const float* l1gv = (const float*)&L1g;
  float4 go, ob;
  float* gov = (float*)&go; float* obv = (float*)&ob;
#pragma unroll
  for (int l = 0; l < 4; ++l) {
    float mx = fmaxf(m0xv[l], m1xv[l]);
    float w0 = __expf(m0xv[l] - mx), w1 = __expf(m1xv[l] - mx);
    float xc = (p0xv[l] * w0 + p1xv[l] * w1) / (l0xv[l] * w0 + l1xv[l] * w1);
    float mg = fmaxf(m0gv[l], m1gv[l]);
    float v0 = __expf(m0gv[l] - mg), v1 = __expf(m1gv[l] - mg);
    float gc = (p0gv[l] * v0 + p1gv[l] * v1) / (l0gv[l] * v0 + l1gv[l] * v1);
    gov[l] = gc;
    obv[l] = gm * xc + al * gc;
  }
  *reinterpret_cast<float4*>(ws + GG_OFF + i) = go;  // GO
  *reinterpret_cast<float4*>(ws + QX_OFF + i) = ob;  // OB
}

// ---------------- K5: u = leaky(conv3x3(leaky(out), c1)), channel-split ----------------
__global__ __launch_bounds__(256) void k_conv1(float* __restrict__ ws,
                                               const float* __restrict__ c1w,
                                               const float* __restrict__ c1b) {
  int blk = blockIdx.x;  // 2048 = b*1024 + og*64 + row
  int row = blk & 63; blk >>= 6;
  int og  = blk & 15; blk >>= 4;
  int b   = blk;
  int o0 = og * 4;
  __shared__ __align__(16) float4 wl4[576];
  __shared__ float part[4][4][64];
  int t = threadIdx.x;
  int wv = t >> 6, px = t & 63;
  {
    float* wlf = (float*)wl4;
    for (int idx = t; idx < 2304; idx += 256)
      wlf[idx] = c1w[(size_t)(o0 + (idx & 3)) * 576 + (idx >> 2)];
  }
  int rm = row - 1, rp = row + 1;
  int rmc = rm < 0 ? 0 : rm, rpc = rp > 63 ? 63 : rp;
  float maskm = rm < 0 ? 0.f : 1.f, maskp = rp > 63 ? 0.f : 1.f;
  int c0 = wv * 16;
  const float* base = ws + OB_OFF + (size_t)b * CN + (size_t)c0 * N_ + px;
  float ra[16], rb[16], rc[16];
#pragma unroll
  for (int i = 0; i < 16; ++i) {
    ra[i] = leaky(base[(size_t)i * N_ + (size_t)rmc * 64]) * maskm;
    rb[i] = leaky(base[(size_t)i * N_ + (size_t)row * 64]);
    rc[i] = leaky(base[(size_t)i * N_ + (size_t)rpc * 64]) * maskp;
  }
  float acc[4] = {};
  auto tap9 = [&](int ch, float va, float vb, float vc) {
    float la = __shfl_up(va, 1, 64);   if (px == 0)  la = 0.f;
    float ga = __shfl_down(va, 1, 64); if (px == 63) ga = 0.f;
    float lb = __shfl_up(vb, 1, 64);   if (px == 0)  lb = 0.f;
    float gb = __shfl_down(vb, 1, 64); if (px == 63) gb = 0.f;
    float lc = __shfl_up(vc, 1, 64);   if (px == 0)  lc = 0.f;
    float gc = __shfl_down(vc, 1, 64); if (px == 63) gc = 0.f;
    float4 w0 = wl4[ch * 9 + 0], w1 = wl4[ch * 9 + 1], w2 = wl4[ch * 9 + 2];
    float4 w3 = wl4[ch * 9 + 3], w4 = wl4[ch * 9 + 4], w5 = wl4[ch * 9 + 5];
    float4 w6 = wl4[ch * 9 + 6], w7 = wl4[ch * 9 + 7], w8 = wl4[ch * 9 + 8];
    acc[0] = fmaf(w0.x, la, fmaf(w1.x, va, fmaf(w2.x, ga, acc[0])));
    acc[1] = fmaf(w0.y, la, fmaf(w1.y, va, fmaf(w2.y, ga, acc[1])));
    acc[2] = fmaf(w0.z, la, fmaf(w1.z, va, fmaf(w2.z, ga, acc[2])));
    acc[3] = fmaf(w0.w, la, fmaf(w1.w, va, fmaf(w2.w, ga, acc[3])));
    acc[0] = fmaf(w3.x, lb, fmaf(w4.x, vb, fmaf(w5.x, gb, acc[0])));
    acc[1] = fmaf(w3.y, lb, fmaf(w4.y, vb, fmaf(w5.y, gb, acc[1])));
    acc[2] = fmaf(w3.z, lb, fmaf(w4.z, vb, fmaf(w5.z, gb, acc[2])));
    acc[3] = fmaf(w3.w, lb, fmaf(w4.w, vb, fmaf(w5.w, gb, acc[3])));
    acc[0] = fmaf(w6.x, lc, fmaf(w7.x, vc, fmaf(w8.x, gc, acc[0])));
    acc[1] = fmaf(w6.y, lc, fmaf(w7.y, vc, fmaf(w8.y, gc, acc[1])));
    acc[2] = fmaf(w6.z, lc, fmaf(w7.z, vc, fmaf(w8.z, gc, acc[2])));
    acc[3] = fmaf(w6.w, lc, fmaf(w7.w, vc, fmaf(w8.w, gc, acc[3])));
  };
  __syncthreads();
#pragma unroll
  for (int i = 0; i < 16; ++i) tap9(c0 + i, ra[i], rb[i], rc[i]);
#pragma unroll
  for (int oo = 0; oo < 4; ++oo) part[wv][oo][px] = acc[oo];
  __syncthreads();
  int oc = t >> 6;
  float s = (part[0][oc][px] + part[1][oc][px]) + (part[2][oc][px] + part[3][oc][px]);
  float* ub = ws + UB_OFF + (size_t)b * CN;
  ub[(size_t)(o0 + oc) * N_ + (size_t)row * 64 + px] = leaky(s + c1b[o0 + oc]);
}

// ---------------- K6: final, channel-split + fused sc dot ----------------
__global__ __launch_bounds__(256) void k_final(const float* __restrict__ ws,
                                               const float* __restrict__ c2w,
                                               const float* __restrict__ c2b,
                                               const float* __restrict__ scw,
                                               const float* __restrict__ scb,
                                               float* __restrict__ out) {
  int blk = blockIdx.x;  // 2048 = b*1024 + og*64 + row
  int row = blk & 63; blk >>= 6;
  int og  = blk & 15; blk >>= 4;
  int b   = blk;
  int o0 = og * 4;
  __shared__ __align__(16) float4 wl4[576];
  __shared__ __align__(16) float4 scl4[64];
  __shared__ float part[4][4][64];
  __shared__ float part2[4][4][64];
  int t = threadIdx.x;
  int wv = t >> 6, px = t & 63;
  {
    float* wlf = (float*)wl4;
    for (int idx = t; idx < 2304; idx += 256)
      wlf[idx] = c2w[(size_t)(o0 + (idx & 3)) * 576 + (idx >> 2)];
    float* sclf = (float*)scl4;
    if (t < 256) {
      int idx = t;
      sclf[idx] = scw[(size_t)(o0 + (idx & 3)) * 64 + (idx >> 2)];
    }
  }
  int rm = row - 1, rp = row + 1;
  int rmc = rm < 0 ? 0 : rm, rpc = rp > 63 ? 63 : rp;
  float maskm = rm < 0 ? 0.f : 1.f, maskp = rp > 63 ? 0.f : 1.f;
  int c0 = wv * 16;
  const float* base = ws + UB_OFF + (size_t)b * CN + (size_t)c0 * N_ + px;
  const float* obb  = ws + OB_OFF + (size_t)b * CN + (size_t)c0 * N_ + (size_t)row * 64 + px;
  float ra[16], rb[16], rc[16], ob[16];
#pragma unroll
  for (int i = 0; i < 16; ++i) {
    ra[i] = base[(size_t)i * N_ + (size_t)rmc * 64] * maskm;
    rb[i] = base[(size_t)i * N_ + (size_t)row * 64];
    rc[i] = base[(size_t)i * N_ + (size_t)rpc * 64] * maskp;
    ob[i] = obb[(size_t)i * N_];
  }
  float acc[4] = {};
  float scp[4] = {};
  auto tap9 = [&](int ch, float va, float vb, float vc) {
    float la = __shfl_up(va, 1, 64);   if (px == 0)  la = 0.f;
    float ga = __shfl_down(va, 1, 64); if (px == 63) ga = 0.f;
    float lb = __shfl_up(vb, 1, 64);   if (px == 0)  lb = 0.f;
    float gb = __shfl_down(vb, 1, 64); if (px == 63) gb = 0.f;
    float lc = __shfl_up(vc, 1, 64);   if (px == 0)  lc = 0.f;
    float gc = __shfl_down(vc, 1, 64); if (px == 63) gc = 0.f;
    float4 w0 = wl4[ch * 9 + 0], w1 = wl4[ch * 9 + 1], w2 = wl4[ch * 9 + 2];
    float4 w3 = wl4[ch * 9 + 3], w4 = wl4[ch * 9 + 4], w5 = wl4[ch * 9 + 5];
    float4 w6 = wl4[ch * 9 + 6], w7 = wl4[ch * 9 + 7], w8 = wl4[ch * 9 + 8];
    acc[0] = fmaf(w0.x, la, fmaf(w1.x, va, fmaf(w2.x, ga, acc[0])));
    acc[1] = fmaf(w0.y, la, fmaf(w1.y, va, fmaf(w2.y, ga, acc[1])));
    acc[2] = fmaf(w0.z, la, fmaf(w1.z, va, fmaf(w2.z, ga, acc[2])));
    acc[3] = fmaf(w0.w, la, fmaf(w1.w, va, fmaf(w2.w, ga, acc[3])));
    acc[0] = fmaf(w3.x, lb, fmaf(w4.x, vb, fmaf(w5.x, gb, acc[0])));
    acc[1] = fmaf(w3.y, lb, fmaf(w4.y, vb, fmaf(w5.y, gb, acc[1])));
    acc[2] = fmaf(w3.z, lb, fmaf(w4.z, vb, fmaf(w5.z, gb, acc[2])));
    acc[3] = fmaf(w3.w, lb, fmaf(w4.w, vb, fmaf(w5.w, gb, acc[3])));
    acc[0] = fmaf(w6.x, lc, fmaf(w7.x, vc, fmaf(w8.x, gc, acc[0])));
    acc[1] = fmaf(w6.y, lc, fmaf(w7.y, vc, fmaf(w8.y, gc, acc[1])));
    acc[2] = fmaf(w6.z, lc, fmaf(w7.z, vc, fmaf(w8.z, gc, acc[2])));
    acc[3] = fmaf(w6.w, lc, fmaf(w7.w, vc, fmaf(w8.w, gc, acc[3])));
  };
  __syncthreads();
#pragma unroll
  for (int i = 0; i < 16; ++i) {
    tap9(c0 + i, ra[i], rb[i], rc[i]);
    float4 s4 = scl4[c0 + i];
    scp[0] = fmaf(s4.x, ob[i], scp[0]);
    scp[1] = fmaf(s4.y, ob[i], scp[1]);
    scp[2] = fmaf(s4.z, ob[i], scp[2]);
    scp[3] = fmaf(s4.w, ob[i], scp[3]);
  }
#pragma unroll
  for (int oo = 0; oo < 4; ++oo) {
    part[wv][oo][px] = acc[oo];
    part2[wv][oo][px] = scp[oo];
  }
  __syncthreads();
  int oc = t >> 6;
  float s  = (part[0][oc][px] + part[1][oc][px]) + (part[2][oc][px] + part[3][oc][px]);
  float sc = (part2[0][oc][px] + part2[1][oc][px]) + (part2[2][oc][px] + part2[3][oc][px]);
  const float* go = ws + GO_OFF + (size_t)b * CN;
  size_t pix = (size_t)row * 64 + px;
  float gvv = go[(size_t)(o0 + oc) * N_ + pix];
  out[(size_t)b * CN + (size_t)(o0 + oc) * N_ + pix] =
      (s + c2b[o0 + oc]) + (sc + scb[o0 + oc]) * gvv;
}

extern "C" void kernel_launch(void* const* d_in, const int* in_sizes, int n_in,
                              void* d_out, int out_size, void* d_ws, size_t ws_size,
                              hipStream_t stream) {
  const float* x     = (const float*)d_in[0];
  const float* guide = (const float*)d_in[1];
  const float* lin_w = (const float*)d_in[2];
  const float* lin_b = (const float*)d_in[3];
  const float* cw    = (const float*)d_in[4];
  const float* xq_w  = (const float*)d_in[5];
  const float* xq_b  = (const float*)d_in[6];
  const float* xk_w  = (const float*)d_in[7];
  const float* xk_b  = (const float*)d_in[8];
  const float* xv_w  = (const float*)d_in[9];
  const float* xv_b  = (const float*)d_in[10];
  const float* gq_w  = (const float*)d_in[11];
  const float* gq_b  = (const float*)d_in[12];
  const float* gk_w  = (const float*)d_in[13];
  const float* gk_b  = (const float*)d_in[14];
  const float* gamma = (const float*)d_in[15];
  const float* alpha = (const float*)d_in[16];
  const float* c1_w  = (const float*)d_in[17];
  const float* c1_b  = (const float*)d_in[18];
  const float* c2_w  = (const float*)d_in[19];
  const float* c2_b  = (const float*)d_in[20];
  const float* sc_w  = (const float*)d_in[21];
  const float* sc_b  = (const float*)d_in[22];
  float* out = (float*)d_out;
  float* ws = (float*)d_ws;

  k_ca<<<256, 64, 0, stream>>>(x, guide, lin_w, lin_b, ws);
  k_coordconv<<<4096, 256, 0, stream>>>(x, guide, cw, ws);
  k_proj<<<640, 256, 0, stream>>>(ws, xq_w, xq_b, xk_w, xk_b, xv_w, xv_b,
                                  gq_w, gq_b, gk_w, gk_b);
  k_attn<<<512, 512, 0, stream>>>(ws);
  k_merge<<<512, 256, 0, stream>>>(ws, gamma, alpha);
  k_conv1<<<2048, 256, 0, stream>>>(ws, c1_w, c1_b);
  k_final<<<2048, 256, 0, stream>>>(ws, c2_w, c2_b, sc_w, sc_b, out);
}

// Round 6
// 286.126 us; speedup vs baseline: 1.0767x; 1.0767x over previous
//
#include <hip/hip_runtime.h>
#include <hip/hip_bf16.h>

using bf16 = __hip_bfloat16;

#define DI __device__ __forceinline__

typedef __attribute__((ext_vector_type(8))) short short8;
typedef __attribute__((ext_vector_type(8))) unsigned short u16x8;
typedef __attribute__((ext_vector_type(4))) unsigned short u16x4;
typedef __attribute__((ext_vector_type(4))) float f32x4;

#define MFMA_BF16 __builtin_amdgcn_mfma_f32_16x16x32_bf16

DI float leaky(float x) { return x > 0.f ? x : 0.1f * x; }

// bf16 split helpers (RNE). x = hi + lo to ~2^-16 relative.
DI unsigned short b16(float x) {
  union { float f; unsigned u; } v; v.f = x;
  unsigned r = v.u + 0x7FFFu + ((v.u >> 16) & 1u);
  return (unsigned short)(r >> 16);
}
DI float fromb16(unsigned short h) {
  union { unsigned u; float f; } v; v.u = ((unsigned)h) << 16; return v.f;
}

// Problem constants: B=2, C=64, H=64, W=64, N=4096. Inputs fp32 (R3/R4).
// NOTE R13: hipLaunchCooperativeKernel fails silently under graph capture here.
// Precision ladder (validated): Q/K split bf16, P hi-only, V hi-only in PV,
// L via ones-row MFMA. R2: swapped QK^T -> lane owns one pixel.
// R4: convs channel-split (block = 1 row x 4 oc, 4 waves x 16 ch, upfront loads).
// R5: attn 8-wave in-block K-split (16 waves/CU) -- REGRESSED: launch_bounds
// (512,4) pinned VGPR to the 64-reg tier vs ~110 live -> scratch spills
// (VGPR 88->64, FETCH +7MB, WRITE +15MB, VALUBusy 40->21).
// R6: same structure, spill fixed: plain launch_bounds(512) (cap 256) and
// V loads split rvA/rvB (4+4 frags, rvB issued after QK under softmax cover)
// -> peak live ~92 regs. R5's numerics (V-direct, packed P, in-block merge)
// passed refcheck, so only the register budget changes here.
static constexpr int N_ = 4096;
static constexpr size_t CN = 262144;
static constexpr size_t BCN = 524288;

// ---- Workspace layout (float indices) ----
static constexpr size_t XG_OFF = 137104;
static constexpr size_t GG_OFF = XG_OFF + BCN;
static constexpr size_t QX_OFF = GG_OFF + BCN;
static constexpr size_t KX_OFF = QX_OFF + BCN;
static constexpr size_t VX_OFF = KX_OFF + BCN;
static constexpr size_t QG_OFF = VX_OFF + BCN;
static constexpr size_t KG_OFF = QG_OFF + BCN;
static constexpr size_t P1X_OFF = KG_OFF + BCN;
static constexpr size_t P1G_OFF = P1X_OFF + BCN;
static constexpr size_t ML_OFF  = P1G_OFF + BCN;
static constexpr size_t MLL_OFF = ML_OFF + 32768;
static constexpr size_t CA_OFF = ML_OFF;   // 256 floats; consumed by coordconv before attn writes ML
static constexpr size_t OB_OFF = QX_OFF;
static constexpr size_t UB_OFF = KX_OFF;
static constexpr size_t GO_OFF = GG_OFF;
static constexpr size_t QXH_U = QX_OFF * 2, QXL_U = QXH_U + BCN;
static constexpr size_t KXH_U = KX_OFF * 2, KXL_U = KXH_U + BCN;
static constexpr size_t VXH_U = VX_OFF * 2;
static constexpr size_t QGH_U = QG_OFF * 2, QGL_U = QGH_U + BCN;
static constexpr size_t KGH_U = KG_OFF * 2, KGL_U = KGH_U + BCN;
// Peak 19.7 MB (validated R6-R14)

// ---------------- K0: channel-attention scales (256 = src*128 + b*64 + ch) ----------------
__global__ __launch_bounds__(64) void k_ca(const float* __restrict__ x,
                                           const float* __restrict__ g,
                                           const float* __restrict__ lw_p,
                                           const float* __restrict__ lb_p,
                                           float* __restrict__ ws) {
  int blk = blockIdx.x;
  int ch = blk & 63; blk >>= 6;
  int b  = blk & 1;  blk >>= 1;
  int src = blk;
  const float* in = (src ? g : x) + ((size_t)(b * 64 + ch)) * N_;
  int t = threadIdx.x;
  float s = 0.f;
#pragma unroll
  for (int i = 0; i < 16; ++i) {
    float4 v = *reinterpret_cast<const float4*>(in + i * 256 + t * 4);
    s += (v.x + v.y) + (v.z + v.w);
  }
#pragma unroll
  for (int d = 1; d < 64; d <<= 1) s += __shfl_xor(s, d, 64);
  if (t == 0) {
    float p = s * (1.f / 4096.f);
    float lwv = lw_p[0], lbv = lb_p[0];
    float h = leaky(lwv * p + lbv);
    ws[CA_OFF + (src * 2 + b) * 64 + ch] = 1.f / (1.f + expf(-(lwv * h + lbv)));
  }
}

// ---------------- K1: coord-conv 3x3, channel-split (1 row x 4 oc / block) ----------------
__global__ __launch_bounds__(256) void k_coordconv(const float* __restrict__ x,
                                                   const float* __restrict__ g,
                                                   const float* __restrict__ cw,
                                                   float* __restrict__ ws) {
  int blk = blockIdx.x;  // 4096 = src*2048 + b*1024 + og*64 + row
  int row = blk & 63; blk >>= 6;
  int og  = blk & 15; blk >>= 4;
  int b   = blk & 1;  blk >>= 1;
  int src = blk;
  int o0 = og * 4;
  const float* in = src ? g : x;
  float* outp = ws + (src ? GG_OFF : XG_OFF);
  __shared__ __align__(16) float4 wl4[594];   // [ch*9+tap] -> 4 oc
  __shared__ float part[4][4][64];
  int t = threadIdx.x;
  int wv = t >> 6, px = t & 63;
  {
    float* wlf = (float*)wl4;
    for (int idx = t; idx < 2376; idx += 256)
      wlf[idx] = cw[(size_t)(o0 + (idx & 3)) * 594 + (idx >> 2)];
  }
  int rm = row - 1, rp = row + 1;
  int rmc = rm < 0 ? 0 : rm, rpc = rp > 63 ? 63 : rp;
  float maskm = rm < 0 ? 0.f : 1.f, maskp = rp > 63 ? 0.f : 1.f;
  int c0 = wv * 16;
  const float* base = in + ((size_t)(b * 64 + c0)) * N_ + px;
  float ra[16], rb[16], rc[16];
#pragma unroll
  for (int i = 0; i < 16; ++i) {
    ra[i] = base[(size_t)i * N_ + (size_t)rmc * 64] * maskm;
    rb[i] = base[(size_t)i * N_ + (size_t)row * 64];
    rc[i] = base[(size_t)i * N_ + (size_t)rpc * 64] * maskp;
  }
  float acc[4] = {};
  auto tap9 = [&](int ch, float va, float vb, float vc) {
    float la = __shfl_up(va, 1, 64);   if (px == 0)  la = 0.f;
    float ga = __shfl_down(va, 1, 64); if (px == 63) ga = 0.f;
    float lb = __shfl_up(vb, 1, 64);   if (px == 0)  lb = 0.f;
    float gb = __shfl_down(vb, 1, 64); if (px == 63) gb = 0.f;
    float lc = __shfl_up(vc, 1, 64);   if (px == 0)  lc = 0.f;
    float gc = __shfl_down(vc, 1, 64); if (px == 63) gc = 0.f;
    float4 w0 = wl4[ch * 9 + 0], w1 = wl4[ch * 9 + 1], w2 = wl4[ch * 9 + 2];
    float4 w3 = wl4[ch * 9 + 3], w4 = wl4[ch * 9 + 4], w5 = wl4[ch * 9 + 5];
    float4 w6 = wl4[ch * 9 + 6], w7 = wl4[ch * 9 + 7], w8 = wl4[ch * 9 + 8];
    acc[0] = fmaf(w0.x, la, fmaf(w1.x, va, fmaf(w2.x, ga, acc[0])));
    acc[1] = fmaf(w0.y, la, fmaf(w1.y, va, fmaf(w2.y, ga, acc[1])));
    acc[2] = fmaf(w0.z, la, fmaf(w1.z, va, fmaf(w2.z, ga, acc[2])));
    acc[3] = fmaf(w0.w, la, fmaf(w1.w, va, fmaf(w2.w, ga, acc[3])));
    acc[0] = fmaf(w3.x, lb, fmaf(w4.x, vb, fmaf(w5.x, gb, acc[0])));
    acc[1] = fmaf(w3.y, lb, fmaf(w4.y, vb, fmaf(w5.y, gb, acc[1])));
    acc[2] = fmaf(w3.z, lb, fmaf(w4.z, vb, fmaf(w5.z, gb, acc[2])));
    acc[3] = fmaf(w3.w, lb, fmaf(w4.w, vb, fmaf(w5.w, gb, acc[3])));
    acc[0] = fmaf(w6.x, lc, fmaf(w7.x, vc, fmaf(w8.x, gc, acc[0])));
    acc[1] = fmaf(w6.y, lc, fmaf(w7.y, vc, fmaf(w8.y, gc, acc[1])));
    acc[2] = fmaf(w6.z, lc, fmaf(w7.z, vc, fmaf(w8.z, gc, acc[2])));
    acc[3] = fmaf(w6.w, lc, fmaf(w7.w, vc, fmaf(w8.w, gc, acc[3])));
  };
  __syncthreads();   // weights ready
#pragma unroll
  for (int i = 0; i < 16; ++i) tap9(c0 + i, ra[i], rb[i], rc[i]);
  if (wv == 3) {
    // ch 64: xx varies along px (zero-padded rows/cols like real channels)
    float xx = (float)px * (2.f / 63.f) - 1.f;
    tap9(64, maskm * xx, xx, maskp * xx);
    // ch 65: yy constant along px, varies by row
    float ya = maskm * ((float)rm * (2.f / 63.f) - 1.f);
    float yb = (float)row * (2.f / 63.f) - 1.f;
    float yc = maskp * ((float)rp * (2.f / 63.f) - 1.f);
    tap9(65, ya, yb, yc);
  }
#pragma unroll
  for (int oo = 0; oo < 4; ++oo) part[wv][oo][px] = acc[oo];
  __syncthreads();
  int oc = t >> 6;
  float s = (part[0][oc][px] + part[1][oc][px]) + (part[2][oc][px] + part[3][oc][px]);
  float cav = ws[CA_OFF + (src * 2 + b) * 64 + o0 + oc];
  outp[((size_t)(b * 64 + o0 + oc)) * N_ + (size_t)row * 64 + px] = s * cav;
}

// ---------------- K2: 1x1 projections; Q/K pre-split hi/lo, V hi-only transposed ----------------
__global__ __launch_bounds__(256) void k_proj(float* __restrict__ ws,
                                              const float* __restrict__ xqw, const float* __restrict__ xqb,
                                              const float* __restrict__ xkw, const float* __restrict__ xkb,
                                              const float* __restrict__ xvw, const float* __restrict__ xvb,
                                              const float* __restrict__ gqw, const float* __restrict__ gqb,
                                              const float* __restrict__ gkw, const float* __restrict__ gkb) {
  int blk = blockIdx.x;  // 5 * 2 * 64
  int pt = blk & 63; blk >>= 6;
  int b  = blk & 1;  blk >>= 1;
  int which = blk;
  size_t in_o;
  const float *wp, *bp;
  size_t hU = 0, lU = 0;
  if (which == 0)      { in_o = XG_OFF; wp = xqw; bp = xqb; hU = QXH_U; lU = QXL_U; }
  else if (which == 1) { in_o = XG_OFF; wp = xkw; bp = xkb; hU = KXH_U; lU = KXL_U; }
  else if (which == 2) { in_o = XG_OFF; wp = xvw; bp = xvb; }
  else if (which == 3) { in_o = GG_OFF; wp = gqw; bp = gqb; hU = QGH_U; lU = QGL_U; }
  else                 { in_o = GG_OFF; wp = gkw; bp = gkb; hU = KGH_U; lU = KGL_U; }

  __shared__ float tile[64 * 64];
  __shared__ float wl[64 * 65];
  __shared__ float bl[64];
  unsigned short* us = (unsigned short*)ws;
  int t = threadIdx.x;
  int pb = pt * 64;
  const float* in0 = ws + in_o + (size_t)b * CN + pb;
  for (int c0 = (t >> 6); c0 < 64; c0 += 4)
    tile[c0 * 64 + (t & 63)] = in0[(size_t)c0 * N_ + (t & 63)];
  for (int idx = t; idx < 4096; idx += 256)
    wl[(idx >> 6) * 65 + (idx & 63)] = wp[idx];
  if (t < 64) bl[t] = bp[t];
  __syncthreads();
  int o = t & 63, grp = t >> 6;
  const float* wr = &wl[o * 65];
  float acc[16];
  float bv = bl[o];
#pragma unroll
  for (int j = 0; j < 16; ++j) acc[j] = bv;
  for (int c = 0; c < 64; ++c) {
    float wv = wr[c];
    const float4* tb = reinterpret_cast<const float4*>(&tile[c * 64 + grp * 16]);
    float4 t0 = tb[0], t1 = tb[1], t2 = tb[2], t3 = tb[3];
    acc[0] = fmaf(wv, t0.x, acc[0]);   acc[1] = fmaf(wv, t0.y, acc[1]);
    acc[2] = fmaf(wv, t0.z, acc[2]);   acc[3] = fmaf(wv, t0.w, acc[3]);
    acc[4] = fmaf(wv, t1.x, acc[4]);   acc[5] = fmaf(wv, t1.y, acc[5]);
    acc[6] = fmaf(wv, t1.z, acc[6]);   acc[7] = fmaf(wv, t1.w, acc[7]);
    acc[8] = fmaf(wv, t2.x, acc[8]);   acc[9] = fmaf(wv, t2.y, acc[9]);
    acc[10] = fmaf(wv, t2.z, acc[10]); acc[11] = fmaf(wv, t2.w, acc[11]);
    acc[12] = fmaf(wv, t3.x, acc[12]); acc[13] = fmaf(wv, t3.y, acc[13]);
    acc[14] = fmaf(wv, t3.z, acc[14]); acc[15] = fmaf(wv, t3.w, acc[15]);
  }
  if (which != 2) {
#pragma unroll
    for (int j = 0; j < 16; ++j) {
      size_t idx = ((size_t)b * N_ + pb + grp * 16 + j) * 64 + o;
      unsigned short hi = b16(acc[j]);
      us[hU + idx] = hi;
      us[lU + idx] = b16(acc[j] - fromb16(hi));
    }
  } else {
    __syncthreads();
    float* ot = wl;
#pragma unroll
    for (int j = 0; j < 16; ++j) ot[o * 65 + grp * 16 + j] = acc[j];
    __syncthreads();
    int o2 = t >> 2;
#pragma unroll
    for (int e = 0; e < 4; ++e) {
      int px = (t & 3) * 16 + e * 4;
      u16x4 hv;
#pragma unroll
      for (int q = 0; q < 4; ++q) hv[q] = b16(ot[o2 * 65 + px + q]);
      size_t idx = ((size_t)(b * 64 + o2)) * N_ + pb + px;
      *reinterpret_cast<u16x4*>(&us[VXH_U + idx]) = hv;
    }
  }
}

// ---------------- K3: MFMA flash attention, 8 waves: in-block K-split + merge ----------------
__global__ __launch_bounds__(512) void k_attn(float* __restrict__ ws) {
  unsigned short* us = (unsigned short*)ws;
  int blk = blockIdx.x;
  int half = blk & 1; blk >>= 1;
  int qt = blk & 63;  blk >>= 6;
  int b  = blk & 1;   blk >>= 1;
  int at = blk;
  const unsigned short* QH = us + (at ? QGH_U : QXH_U);
  const unsigned short* QL = us + (at ? QGL_U : QXL_U);
  const unsigned short* KHg = us + (at ? KGH_U : KXH_U);
  const unsigned short* KLg = us + (at ? KGL_U : KXL_U);
  const unsigned short* VHg = us + VXH_U;
  float* Pg = ws + (at ? (half ? P1G_OFF : GG_OFF) : (half ? P1X_OFF : XG_OFF))
            + (size_t)b * CN + qt * 64;

  // per group (g=0,1): Kh dbuf [2][4096] | Kl dbuf [2][4096] | Ph [4096]
  __shared__ __align__(16) unsigned short lds[40960];   // 80 KB total

  int t = threadIdx.x;
  int g = t >> 8, tg = t & 255;
  int w = tg >> 6, lane = tg & 63, quad = lane >> 4, l15 = lane & 15;
  int swz = l15 & 7;
  unsigned short* Kh0 = lds + g * 20480;
  unsigned short* Kl0 = lds + g * 20480 + 8192;
  unsigned short* Phg = lds + g * 20480 + 16384;

  short8 qh[2], ql[2];
  {
    size_t qbase = ((size_t)b * N_ + qt * 64 + 16 * w + l15) * 64;
#pragma unroll
    for (int ks = 0; ks < 2; ++ks) {
      qh[ks] = *reinterpret_cast<const short8*>(&QH[qbase + ks * 32 + quad * 8]);
      ql[ks] = *reinterpret_cast<const short8*>(&QL[qbase + ks * 32 + quad * 8]);
    }
  }

  short8 ones;
#pragma unroll
  for (int j = 0; j < 8; ++j) ones[j] = (short)0x3F80;  // bf16 1.0

  int mt0 = half * 32 + g * 16;   // this group's 16 K-tiles

  u16x8 rkh[2], rkl[2];
  size_t ko = ((size_t)b * N_ + (size_t)mt0 * 64 + (tg >> 3)) * 64 + (size_t)(tg & 7) * 8;
  auto prefetchK = [&]() {
    rkh[0] = *reinterpret_cast<const u16x8*>(&KHg[ko]);
    rkl[0] = *reinterpret_cast<const u16x8*>(&KLg[ko]);
    rkh[1] = *reinterpret_cast<const u16x8*>(&KHg[ko + 2048]);
    rkl[1] = *reinterpret_cast<const u16x8*>(&KLg[ko + 2048]);
    ko += 4096;
  };
  int wr0 = tg >> 3, wch = tg & 7;
  int woff = wr0 * 64 + ((wch ^ (wr0 & 7)) << 3);
  auto writebufK = [&](int par) {
    *reinterpret_cast<u16x8*>(&Kh0[par * 4096 + woff]) = rkh[0];
    *reinterpret_cast<u16x8*>(&Kl0[par * 4096 + woff]) = rkl[0];
    *reinterpret_cast<u16x8*>(&Kh0[par * 4096 + woff + 2048]) = rkh[1];
    *reinterpret_cast<u16x8*>(&Kl0[par * 4096 + woff + 2048]) = rkl[1];
  };

  // V straight from global: lane needs V[ch=cs*16+l15][mt*64 + ks*32 + quad*8 ..+7]
  size_t vb = ((size_t)(b * 64 + l15)) * N_ + (size_t)mt0 * 64 + quad * 8;

  f32x4 Oa[4] = {{0.f, 0.f, 0.f, 0.f}, {0.f, 0.f, 0.f, 0.f},
                 {0.f, 0.f, 0.f, 0.f}, {0.f, 0.f, 0.f, 0.f}};
  f32x4 La = {0.f, 0.f, 0.f, 0.f};   // L via ones-row MFMA (rows identical)
  float M = -1e30f;                  // per-lane: pixel n = 16w + l15 (quad-uniform)

  int phb = (16 * w + l15) * 64;
  int mh = quad >> 1, mlw = (quad & 1) * 4;

  prefetchK();
  writebufK(0);
  __syncthreads();
  for (int it = 0; it < 16; ++it) {
    int pb = it & 1;
    // V ks=0 loads for THIS tile: 4 x 16B, retire under the QK phase
    u16x8 rvA[4];
#pragma unroll
    for (int cs = 0; cs < 4; ++cs)
      rvA[cs] = *reinterpret_cast<const u16x8*>(&VHg[vb + (size_t)cs * 16 * N_]);
    if (it + 1 < 16) prefetchK();

    // S^T[m][n]: m = ms*16 + quad*4 + reg, n = 16w + l15 (swapped operands)
    f32x4 S[4];
    __builtin_amdgcn_s_setprio(1);
#pragma unroll
    for (int ms = 0; ms < 4; ++ms) {
      f32x4 a0 = {0.f, 0.f, 0.f, 0.f}, a1 = {0.f, 0.f, 0.f, 0.f};
      int row = ms * 16 + l15;
#pragma unroll
      for (int ks = 0; ks < 2; ++ks) {
        int off = pb * 4096 + row * 64 + (((ks * 4 + quad) ^ swz) << 3);
        short8 khf = *reinterpret_cast<const short8*>(&Kh0[off]);
        short8 klf = *reinterpret_cast<const short8*>(&Kl0[off]);
        f32x4& a = ks ? a1 : a0;
        a = MFMA_BF16(khf, ql[ks], a, 0, 0, 0);
        a = MFMA_BF16(klf, qh[ks], a, 0, 0, 0);
        a = MFMA_BF16(khf, qh[ks], a, 0, 0, 0);
      }
      S[ms] = a0 + a1;
    }
    __builtin_amdgcn_s_setprio(0);

    // V ks=1 loads: issued here, covered by softmax + PV ks=0
    u16x8 rvB[4];
#pragma unroll
    for (int cs = 0; cs < 4; ++cs)
      rvB[cs] = *reinterpret_cast<const u16x8*>(&VHg[vb + (size_t)cs * 16 * N_ + 32]);
    vb += 64;

    // in-lane max (max3-shaped) + 2-step cross-quad butterfly
    float t0 = fmaxf(fmaxf(S[0][0], S[0][1]), S[0][2]);
    float t1 = fmaxf(fmaxf(S[0][3], S[1][0]), S[1][1]);
    float t2 = fmaxf(fmaxf(S[1][2], S[1][3]), S[2][0]);
    float t3 = fmaxf(fmaxf(S[2][1], S[2][2]), S[2][3]);
    float t4 = fmaxf(fmaxf(S[3][0], S[3][1]), S[3][2]);
    float t5 = fmaxf(fmaxf(t0, t1), t2);
    float t6 = fmaxf(fmaxf(t3, t4), S[3][3]);
    float tm = fmaxf(t5, t6);
    tm = fmaxf(tm, __shfl_xor(tm, 16, 64));
    tm = fmaxf(tm, __shfl_xor(tm, 32, 64));
    float mn = fmaxf(M, tm);
    float al = __expf(M - mn);
    M = mn;
#pragma unroll
    for (int ms = 0; ms < 4; ++ms) {
      int goff = phb + ((((ms << 1) + mh) ^ swz) << 3) + mlw;
      unsigned lo = (unsigned)b16(__expf(S[ms][0] - mn)) |
                    ((unsigned)b16(__expf(S[ms][1] - mn)) << 16);
      unsigned hi = (unsigned)b16(__expf(S[ms][2] - mn)) |
                    ((unsigned)b16(__expf(S[ms][3] - mn)) << 16);
      uint2 pk; pk.x = lo; pk.y = hi;
      *reinterpret_cast<uint2*>(&Phg[goff]) = pk;   // 8B store, wave-private rows
    }
#pragma unroll
    for (int cs = 0; cs < 4; ++cs) {
      Oa[cs][0] *= al; Oa[cs][1] *= al; Oa[cs][2] *= al; Oa[cs][3] *= al;
    }
    La[0] *= al;

    // O^T += V^T P^T (V from regs): 10 MFMAs incl. 2 ones-row for L
    __builtin_amdgcn_s_setprio(1);
    {
      int poff = phb + (((0 * 4 + quad) ^ swz) << 3);
      short8 phf = *reinterpret_cast<const short8*>(&Phg[poff]);
      La = MFMA_BF16(ones, phf, La, 0, 0, 0);
#pragma unroll
      for (int cs = 0; cs < 4; ++cs)
        Oa[cs] = MFMA_BF16((short8)rvA[cs], phf, Oa[cs], 0, 0, 0);
    }
    {
      int poff = phb + (((1 * 4 + quad) ^ swz) << 3);
      short8 phf = *reinterpret_cast<const short8*>(&Phg[poff]);
      La = MFMA_BF16(ones, phf, La, 0, 0, 0);
#pragma unroll
      for (int cs = 0; cs < 4; ++cs)
        Oa[cs] = MFMA_BF16((short8)rvB[cs], phf, Oa[cs], 0, 0, 0);
    }
    __builtin_amdgcn_s_setprio(0);

    if (it + 1 < 16) writebufK(pb ^ 1);  // fenced by previous iteration's barrier
    __syncthreads();
  }

  // ---- in-block merge of the two 16-tile groups ----
  float* exch = (float*)(lds + 20480);   // group 1's K region (done with it)
  float Lv = La[0];
  if (g == 1) {
#pragma unroll
    for (int cs = 0; cs < 4; ++cs)
#pragma unroll
      for (int r = 0; r < 4; ++r) exch[tg * 16 + cs * 4 + r] = Oa[cs][r];
    if (quad == 0) {
      exch[4096 + 16 * w + l15] = M;
      exch[4160 + 16 * w + l15] = Lv;
    }
  }
  __syncthreads();
  if (g == 0) {
    int n = 16 * w + l15;
    float MB = exch[4096 + n], LB = exch[4160 + n];
    float Mm = fmaxf(M, MB);
    float wA = __expf(M - Mm), wB = __expf(MB - Mm);
    float Lm = Lv * wA + LB * wB;
#pragma unroll
    for (int cs = 0; cs < 4; ++cs) {
#pragma unroll
      for (int r = 0; r < 4; ++r) {
        float o = Oa[cs][r] * wA + exch[tg * 16 + cs * 4 + r] * wB;
        int c = cs * 16 + quad * 4 + r;
        Pg[(size_t)c * N_ + n] = o;
      }
    }
    if (quad == 0) {
      int mlb = ((at * 2 + half) * 2 + b) * 4096 + qt * 64 + n;
      ws[ML_OFF + mlb] = Mm;
      ws[MLL_OFF + mlb] = Lm;
    }
  }
}

// ---------------- K4: merge halves + combine ----------------
__global__ __launch_bounds__(256) void k_merge(float* __restrict__ ws,
                                               const float* __restrict__ gm_p,
                                               const float* __restrict__ al_p) {
  size_t i4 = (size_t)blockIdx.x * 256 + threadIdx.x;
  size_t i = i4 * 4;
  int n = (int)(i & 4095);
  int b = (int)(i >> 18);
  float gm = gm_p[0], al = al_p[0];
  float4 p0x = *reinterpret_cast<const float4*>(ws + XG_OFF + i);
  float4 p1x = *reinterpret_cast<const float4*>(ws + P1X_OFF + i);
  float4 p0g = *reinterpret_cast<const float4*>(ws + GG_OFF + i);
  float4 p1g = *reinterpret_cast<const float4*>(ws + P1G_OFF + i);
  float4 M0x = *reinterpret_cast<const float4*>(ws + ML_OFF  + (0 + b) * 4096 + n);
  float4 L0x = *reinterpret_cast<const float4*>(ws + MLL_OFF + (0 + b) * 4096 + n);
  float4 M1x = *reinterpret_cast<const float4*>(ws + ML_OFF  + (2 + b) * 4096 + n);
  float4 L1x = *reinterpret_cast<const float4*>(ws + MLL_OFF + (2 + b) * 4096 + n);
  float4 M0g = *reinterpret_cast<const float4*>(ws + ML_OFF  + (4 + b) * 4096 + n);
  float4 L0g = *reinterpret_cast<const float4*>(ws + MLL_OFF + (4 + b) * 4096 + n);
  float4 M1g = *reinterpret_cast<const float4*>(ws + ML_OFF  + (6 + b) * 4096 + n);
  float4 L1g = *reinterpret_cast<const float4*>(ws + MLL_OFF + (6 + b) * 4096 + n);
  const float* p0xv = (const float*)&p0x; const float* p1xv = (const float*)&p1x;
  const float* p0gv = (const float*)&p0g; const float* p1gv = (const float*)&p1g;
  const float* m0xv = (const float*)&M0x; const float* l0xv = (const float*)&L0x;
  const float* m1xv = (const float*)&M1x; const float* l1xv = (const float*)&L1x;
  const float* m0gv = (const float*)&M0g; const float* l0gv = (const float*)&L0g;
  const float* m1gv = (const float*)&M1g; const float* l1gv = (const float*)&L1g;
  float4 go, ob;
  float* gov = (float*)&go; float* obv = (float*)&ob;
#pragma unroll
  for (int l = 0; l < 4; ++l) {
    float mx = fmaxf(m0xv[l], m1xv[l]);
    float w0 = __expf(m0xv[l] - mx), w1 = __expf(m1xv[l] - mx);
    float xc = (p0xv[l] * w0 + p1xv[l] * w1) / (l0xv[l] * w0 + l1xv[l] * w1);
    float mg = fmaxf(m0gv[l], m1gv[l]);
    float v0 = __expf(m0gv[l] - mg), v1 = __expf(m1gv[l] - mg);
    float gc = (p0gv[l] * v0 + p1gv[l] * v1) / (l0gv[l] * v0 + l1gv[l] * v1);
    gov[l] = gc;
    obv[l] = gm * xc + al * gc;
  }
  *reinterpret_cast<float4*>(ws + GG_OFF + i) = go;  // GO
  *reinterpret_cast<float4*>(ws + QX_OFF + i) = ob;  // OB
}

// ---------------- K5: u = leaky(conv3x3(leaky(out), c1)), channel-split ----------------
__global__ __launch_bounds__(256) void k_conv1(float* __restrict__ ws,
                                               const float* __restrict__ c1w,
                                               const float* __restrict__ c1b) {
  int blk = blockIdx.x;  // 2048 = b*1024 + og*64 + row
  int row = blk & 63; blk >>= 6;
  int og  = blk & 15; blk >>= 4;
  int b   = blk;
  int o0 = og * 4;
  __shared__ __align__(16) float4 wl4[576];
  __shared__ float part[4][4][64];
  int t = threadIdx.x;
  int wv = t >> 6, px = t & 63;
  {
    float* wlf = (float*)wl4;
    for (int idx = t; idx < 2304; idx += 256)
      wlf[idx] = c1w[(size_t)(o0 + (idx & 3)) * 576 + (idx >> 2)];
  }
  int rm = row - 1, rp = row + 1;
  int rmc = rm < 0 ? 0 : rm, rpc = rp > 63 ? 63 : rp;
  float maskm = rm < 0 ? 0.f : 1.f, maskp = rp > 63 ? 0.f : 1.f;
  int c0 = wv * 16;
  const float* base = ws + OB_OFF + (size_t)b * CN + (size_t)c0 * N_ + px;
  float ra[16], rb[16], rc[16];
#pragma unroll
  for (int i = 0; i < 16; ++i) {
    ra[i] = leaky(base[(size_t)i * N_ + (size_t)rmc * 64]) * maskm;
    rb[i] = leaky(base[(size_t)i * N_ + (size_t)row * 64]);
    rc[i] = leaky(base[(size_t)i * N_ + (size_t)rpc * 64]) * maskp;
  }
  float acc[4] = {};
  auto tap9 = [&](int ch, float va, float vb, float vc) {
    float la = __shfl_up(va, 1, 64);   if (px == 0)  la = 0.f;
    float ga = __shfl_down(va, 1, 64); if (px == 63) ga = 0.f;
    float lb = __shfl_up(vb, 1, 64);   if (px == 0)  lb = 0.f;
    float gb = __shfl_down(vb, 1, 64); if (px == 63) gb = 0.f;
    float lc = __shfl_up(vc, 1, 64);   if (px == 0)  lc = 0.f;
    float gc = __shfl_down(vc, 1, 64); if (px == 63) gc = 0.f;
    float4 w0 = wl4[ch * 9 + 0], w1 = wl4[ch * 9 + 1], w2 = wl4[ch * 9 + 2];
    float4 w3 = wl4[ch * 9 + 3], w4 = wl4[ch * 9 + 4], w5 = wl4[ch * 9 + 5];
    float4 w6 = wl4[ch * 9 + 6], w7 = wl4[ch * 9 + 7], w8 = wl4[ch * 9 + 8];
    acc[0] = fmaf(w0.x, la, fmaf(w1.x, va, fmaf(w2.x, ga, acc[0])));
    acc[1] = fmaf(w0.y, la, fmaf(w1.y, va, fmaf(w2.y, ga, acc[1])));
    acc[2] = fmaf(w0.z, la, fmaf(w1.z, va, fmaf(w2.z, ga, acc[2])));
    acc[3] = fmaf(w0.w, la, fmaf(w1.w, va, fmaf(w2.w, ga, acc[3])));
    acc[0] = fmaf(w3.x, lb, fmaf(w4.x, vb, fmaf(w5.x, gb, acc[0])));
    acc[1] = fmaf(w3.y, lb, fmaf(w4.y, vb, fmaf(w5.y, gb, acc[1])));
    acc[2] = fmaf(w3.z, lb, fmaf(w4.z, vb, fmaf(w5.z, gb, acc[2])));
    acc[3] = fmaf(w3.w, lb, fmaf(w4.w, vb, fmaf(w5.w, gb, acc[3])));
    acc[0] = fmaf(w6.x, lc, fmaf(w7.x, vc, fmaf(w8.x, gc, acc[0])));
    acc[1] = fmaf(w6.y, lc, fmaf(w7.y, vc, fmaf(w8.y, gc, acc[1])));
    acc[2] = fmaf(w6.z, lc, fmaf(w7.z, vc, fmaf(w8.z, gc, acc[2])));
    acc[3] = fmaf(w6.w, lc, fmaf(w7.w, vc, fmaf(w8.w, gc, acc[3])));
  };
  __syncthreads();
#pragma unroll
  for (int i = 0; i < 16; ++i) tap9(c0 + i, ra[i], rb[i], rc[i]);
#pragma unroll
  for (int oo = 0; oo < 4; ++oo) part[wv][oo][px] = acc[oo];
  __syncthreads();
  int oc = t >> 6;
  float s = (part[0][oc][px] + part[1][oc][px]) + (part[2][oc][px] + part[3][oc][px]);
  float* ub = ws + UB_OFF + (size_t)b * CN;
  ub[(size_t)(o0 + oc) * N_ + (size_t)row * 64 + px] = leaky(s + c1b[o0 + oc]);
}

// ---------------- K6: final, channel-split + fused sc dot ----------------
__global__ __launch_bounds__(256) void k_final(const float* __restrict__ ws,
                                               const float* __restrict__ c2w,
                                               const float* __restrict__ c2b,
                                               const float* __restrict__ scw,
                                               const float* __restrict__ scb,
                                               float* __restrict__ out) {
  int blk = blockIdx.x;  // 2048 = b*1024 + og*64 + row
  int row = blk & 63; blk >>= 6;
  int og  = blk & 15; blk >>= 4;
  int b   = blk;
  int o0 = og * 4;
  __shared__ __align__(16) float4 wl4[576];
  __shared__ __align__(16) float4 scl4[64];
  __shared__ float part[4][4][64];
  __shared__ float part2[4][4][64];
  int t = threadIdx.x;
  int wv = t >> 6, px = t & 63;
  {
    float* wlf = (float*)wl4;
    for (int idx = t; idx < 2304; idx += 256)
      wlf[idx] = c2w[(size_t)(o0 + (idx & 3)) * 576 + (idx >> 2)];
    float* sclf = (float*)scl4;
    if (t < 256) {
      int idx = t;
      sclf[idx] = scw[(size_t)(o0 + (idx & 3)) * 64 + (idx >> 2)];
    }
  }
  int rm = row - 1, rp = row + 1;
  int rmc = rm < 0 ? 0 : rm, rpc = rp > 63 ? 63 : rp;
  float maskm = rm < 0 ? 0.f : 1.f, maskp = rp > 63 ? 0.f : 1.f;
  int c0 = wv * 16;
  const float* base = ws + UB_OFF + (size_t)b * CN + (size_t)c0 * N_ + px;
  const float* obb  = ws + OB_OFF + (size_t)b * CN + (size_t)c0 * N_ + (size_t)row * 64 + px;
  float ra[16], rb[16], rc[16], ob[16];
#pragma unroll
  for (int i = 0; i < 16; ++i) {
    ra[i] = base[(size_t)i * N_ + (size_t)rmc * 64] * maskm;
    rb[i] = base[(size_t)i * N_ + (size_t)row * 64];
    rc[i] = base[(size_t)i * N_ + (size_t)rpc * 64] * maskp;
    ob[i] = obb[(size_t)i * N_];
  }
  float acc[4] = {};
  float scp[4] = {};
  auto tap9 = [&](int ch, float va, float vb, float vc) {
    float la = __shfl_up(va, 1, 64);   if (px == 0)  la = 0.f;
    float ga = __shfl_down(va, 1, 64); if (px == 63) ga = 0.f;
    float lb = __shfl_up(vb, 1, 64);   if (px == 0)  lb = 0.f;
    float gb = __shfl_down(vb, 1, 64); if (px == 63) gb = 0.f;
    float lc = __shfl_up(vc, 1, 64);   if (px == 0)  lc = 0.f;
    float gc = __shfl_down(vc, 1, 64); if (px == 63) gc = 0.f;
    float4 w0 = wl4[ch * 9 + 0], w1 = wl4[ch * 9 + 1], w2 = wl4[ch * 9 + 2];
    float4 w3 = wl4[ch * 9 + 3], w4 = wl4[ch * 9 + 4], w5 = wl4[ch * 9 + 5];
    float4 w6 = wl4[ch * 9 + 6], w7 = wl4[ch * 9 + 7], w8 = wl4[ch * 9 + 8];
    acc[0] = fmaf(w0.x, la, fmaf(w1.x, va, fmaf(w2.x, ga, acc[0])));
    acc[1] = fmaf(w0.y, la, fmaf(w1.y, va, fmaf(w2.y, ga, acc[1])));
    acc[2] = fmaf(w0.z, la, fmaf(w1.z, va, fmaf(w2.z, ga, acc[2])));
    acc[3] = fmaf(w0.w, la, fmaf(w1.w, va, fmaf(w2.w, ga, acc[3])));
    acc[0] = fmaf(w3.x, lb, fmaf(w4.x, vb, fmaf(w5.x, gb, acc[0])));
    acc[1] = fmaf(w3.y, lb, fmaf(w4.y, vb, fmaf(w5.y, gb, acc[1])));
    acc[2] = fmaf(w3.z, lb, fmaf(w4.z, vb, fmaf(w5.z, gb, acc[2])));
    acc[3] = fmaf(w3.w, lb, fmaf(w4.w, vb, fmaf(w5.w, gb, acc[3])));
    acc[0] = fmaf(w6.x, lc, fmaf(w7.x, vc, fmaf(w8.x, gc, acc[0])));
    acc[1] = fmaf(w6.y, lc, fmaf(w7.y, vc, fmaf(w8.y, gc, acc[1])));
    acc[2] = fmaf(w6.z, lc, fmaf(w7.z, vc, fmaf(w8.z, gc, acc[2])));
    acc[3] = fmaf(w6.w, lc, fmaf(w7.w, vc, fmaf(w8.w, gc, acc[3])));
  };
  __syncthreads();
#pragma unroll
  for (int i = 0; i < 16; ++i) {
    tap9(c0 + i, ra[i], rb[i], rc[i]);
    float4 s4 = scl4[c0 + i];
    scp[0] = fmaf(s4.x, ob[i], scp[0]);
    scp[1] = fmaf(s4.y, ob[i], scp[1]);
    scp[2] = fmaf(s4.z, ob[i], scp[2]);
    scp[3] = fmaf(s4.w, ob[i], scp[3]);
  }
#pragma unroll
  for (int oo = 0; oo < 4; ++oo) {
    part[wv][oo][px] = acc[oo];
    part2[wv][oo][px] = scp[oo];
  }
  __syncthreads();
  int oc = t >> 6;
  float s  = (part[0][oc][px] + part[1][oc][px]) + (part[2][oc][px] + part[3][oc][px]);
  float sc = (part2[0][oc][px] + part2[1][oc][px]) + (part2[2][oc][px] + part2[3][oc][px]);
  const float* go = ws + GO_OFF + (size_t)b * CN;
  size_t pix = (size_t)row * 64 + px;
  float gvv = go[(size_t)(o0 + oc) * N_ + pix];
  out[(size_t)b * CN + (size_t)(o0 + oc) * N_ + pix] =
      (s + c2b[o0 + oc]) + (sc + scb[o0 + oc]) * gvv;
}

extern "C" void kernel_launch(void* const* d_in, const int* in_sizes, int n_in,
                              void* d_out, int out_size, void* d_ws, size_t ws_size,
                              hipStream_t stream) {
  const float* x     = (const float*)d_in[0];
  const float* guide = (const float*)d_in[1];
  const float* lin_w = (const float*)d_in[2];
  const float* lin_b = (const float*)d_in[3];
  const float* cw    = (const float*)d_in[4];
  const float* xq_w  = (const float*)d_in[5];
  const float* xq_b  = (const float*)d_in[6];
  const float* xk_w  = (const float*)d_in[7];
  const float* xk_b  = (const float*)d_in[8];
  const float* xv_w  = (const float*)d_in[9];
  const float* xv_b  = (const float*)d_in[10];
  const float* gq_w  = (const float*)d_in[11];
  const float* gq_b  = (const float*)d_in[12];
  const float* gk_w  = (const float*)d_in[13];
  const float* gk_b  = (const float*)d_in[14];
  const float* gamma = (const float*)d_in[15];
  const float* alpha = (const float*)d_in[16];
  const float* c1_w  = (const float*)d_in[17];
  const float* c1_b  = (const float*)d_in[18];
  const float* c2_w  = (const float*)d_in[19];
  const float* c2_b  = (const float*)d_in[20];
  const float* sc_w  = (const float*)d_in[21];
  const float* sc_b  = (const float*)d_in[22];
  float* out = (float*)d_out;
  float* ws = (float*)d_ws;

  k_ca<<<256, 64, 0, stream>>>(x, guide, lin_w, lin_b, ws);
  k_coordconv<<<4096, 256, 0, stream>>>(x, guide, cw, ws);
  k_proj<<<640, 256, 0, stream>>>(ws, xq_w, xq_b, xk_w, xk_b, xv_w, xv_b,
                                  gq_w, gq_b, gk_w, gk_b);
  k_attn<<<512, 512, 0, stream>>>(ws);
  k_merge<<<512, 256, 0, stream>>>(ws, gamma, alpha);
  k_conv1<<<2048, 256, 0, stream>>>(ws, c1_w, c1_b);
  k_final<<<2048, 256, 0, stream>>>(ws, c2_w, c2_b, sc_w, sc_b, out);
}

// Round 7
// 277.111 us; speedup vs baseline: 1.1117x; 1.0325x over previous
//
#include <hip/hip_runtime.h>
#include <hip/hip_bf16.h>

using bf16 = __hip_bfloat16;

#define DI __device__ __forceinline__

typedef __attribute__((ext_vector_type(8))) short short8;
typedef __attribute__((ext_vector_type(8))) unsigned short u16x8;
typedef __attribute__((ext_vector_type(4))) unsigned short u16x4;
typedef __attribute__((ext_vector_type(4))) float f32x4;

#define MFMA_BF16 __builtin_amdgcn_mfma_f32_16x16x32_bf16

DI float leaky(float x) { return x > 0.f ? x : 0.1f * x; }

// bf16 split helpers (RNE). x = hi + lo to ~2^-16 relative.
DI unsigned short b16(float x) {
  union { float f; unsigned u; } v; v.f = x;
  unsigned r = v.u + 0x7FFFu + ((v.u >> 16) & 1u);
  return (unsigned short)(r >> 16);
}
DI float fromb16(unsigned short h) {
  union { unsigned u; float f; } v; v.u = ((unsigned)h) << 16; return v.f;
}

// Problem constants: B=2, C=64, H=64, W=64, N=4096. Inputs fp32 (R3/R4).
// NOTE R13: hipLaunchCooperativeKernel fails silently under graph capture here.
// Precision ladder (validated): Q/K split bf16, P hi-only, V hi-only in PV,
// L via ones-row MFMA. R2: swapped QK^T -> lane owns one pixel.
// R4: convs channel-split (block = 1 row x 4 oc, 4 waves x 16 ch, upfront loads).
// R5/R6 lesson: 8-wave in-block K-split NEVER beat R4's 4-wave form (84 vs
// 71.7 us even spill-free) -- 8-wave barrier domain + doubled K LDS streams;
// waves/CU is structurally 8 (2048 waves / 256 CUs) without more partials.
// R7: R4 structure + only the validated wins: V direct from global (drop Vth,
// LDS 56->40KB, kills 8 ds_reads + 2 LDS writes per tile; rvA under QK cover,
// rvB under softmax cover), packed-P uint2 stores, max3 tree.
static constexpr int N_ = 4096;
static constexpr size_t CN = 262144;
static constexpr size_t BCN = 524288;

// ---- Workspace layout (float indices) ----
static constexpr size_t XG_OFF = 137104;
static constexpr size_t GG_OFF = XG_OFF + BCN;
static constexpr size_t QX_OFF = GG_OFF + BCN;
static constexpr size_t KX_OFF = QX_OFF + BCN;
static constexpr size_t VX_OFF = KX_OFF + BCN;
static constexpr size_t QG_OFF = VX_OFF + BCN;
static constexpr size_t KG_OFF = QG_OFF + BCN;
static constexpr size_t P1X_OFF = KG_OFF + BCN;
static constexpr size_t P1G_OFF = P1X_OFF + BCN;
static constexpr size_t ML_OFF  = P1G_OFF + BCN;
static constexpr size_t MLL_OFF = ML_OFF + 32768;
static constexpr size_t CA_OFF = ML_OFF;   // 256 floats; consumed by coordconv before attn writes ML
static constexpr size_t OB_OFF = QX_OFF;
static constexpr size_t UB_OFF = KX_OFF;
static constexpr size_t GO_OFF = GG_OFF;
static constexpr size_t QXH_U = QX_OFF * 2, QXL_U = QXH_U + BCN;
static constexpr size_t KXH_U = KX_OFF * 2, KXL_U = KXH_U + BCN;
static constexpr size_t VXH_U = VX_OFF * 2;
static constexpr size_t QGH_U = QG_OFF * 2, QGL_U = QGH_U + BCN;
static constexpr size_t KGH_U = KG_OFF * 2, KGL_U = KGH_U + BCN;
// Peak 19.7 MB (validated R6-R14)

// ---------------- K0: channel-attention scales (256 = src*128 + b*64 + ch) ----------------
__global__ __launch_bounds__(64) void k_ca(const float* __restrict__ x,
                                           const float* __restrict__ g,
                                           const float* __restrict__ lw_p,
                                           const float* __restrict__ lb_p,
                                           float* __restrict__ ws) {
  int blk = blockIdx.x;
  int ch = blk & 63; blk >>= 6;
  int b  = blk & 1;  blk >>= 1;
  int src = blk;
  const float* in = (src ? g : x) + ((size_t)(b * 64 + ch)) * N_;
  int t = threadIdx.x;
  float s = 0.f;
#pragma unroll
  for (int i = 0; i < 16; ++i) {
    float4 v = *reinterpret_cast<const float4*>(in + i * 256 + t * 4);
    s += (v.x + v.y) + (v.z + v.w);
  }
#pragma unroll
  for (int d = 1; d < 64; d <<= 1) s += __shfl_xor(s, d, 64);
  if (t == 0) {
    float p = s * (1.f / 4096.f);
    float lwv = lw_p[0], lbv = lb_p[0];
    float h = leaky(lwv * p + lbv);
    ws[CA_OFF + (src * 2 + b) * 64 + ch] = 1.f / (1.f + expf(-(lwv * h + lbv)));
  }
}

// ---------------- K1: coord-conv 3x3, channel-split (1 row x 4 oc / block) ----------------
__global__ __launch_bounds__(256) void k_coordconv(const float* __restrict__ x,
                                                   const float* __restrict__ g,
                                                   const float* __restrict__ cw,
                                                   float* __restrict__ ws) {
  int blk = blockIdx.x;  // 4096 = src*2048 + b*1024 + og*64 + row
  int row = blk & 63; blk >>= 6;
  int og  = blk & 15; blk >>= 4;
  int b   = blk & 1;  blk >>= 1;
  int src = blk;
  int o0 = og * 4;
  const float* in = src ? g : x;
  float* outp = ws + (src ? GG_OFF : XG_OFF);
  __shared__ __align__(16) float4 wl4[594];   // [ch*9+tap] -> 4 oc
  __shared__ float part[4][4][64];
  int t = threadIdx.x;
  int wv = t >> 6, px = t & 63;
  {
    float* wlf = (float*)wl4;
    for (int idx = t; idx < 2376; idx += 256)
      wlf[idx] = cw[(size_t)(o0 + (idx & 3)) * 594 + (idx >> 2)];
  }
  int rm = row - 1, rp = row + 1;
  int rmc = rm < 0 ? 0 : rm, rpc = rp > 63 ? 63 : rp;
  float maskm = rm < 0 ? 0.f : 1.f, maskp = rp > 63 ? 0.f : 1.f;
  int c0 = wv * 16;
  const float* base = in + ((size_t)(b * 64 + c0)) * N_ + px;
  float ra[16], rb[16], rc[16];
#pragma unroll
  for (int i = 0; i < 16; ++i) {
    ra[i] = base[(size_t)i * N_ + (size_t)rmc * 64] * maskm;
    rb[i] = base[(size_t)i * N_ + (size_t)row * 64];
    rc[i] = base[(size_t)i * N_ + (size_t)rpc * 64] * maskp;
  }
  float acc[4] = {};
  auto tap9 = [&](int ch, float va, float vb, float vc) {
    float la = __shfl_up(va, 1, 64);   if (px == 0)  la = 0.f;
    float ga = __shfl_down(va, 1, 64); if (px == 63) ga = 0.f;
    float lb = __shfl_up(vb, 1, 64);   if (px == 0)  lb = 0.f;
    float gb = __shfl_down(vb, 1, 64); if (px == 63) gb = 0.f;
    float lc = __shfl_up(vc, 1, 64);   if (px == 0)  lc = 0.f;
    float gc = __shfl_down(vc, 1, 64); if (px == 63) gc = 0.f;
    float4 w0 = wl4[ch * 9 + 0], w1 = wl4[ch * 9 + 1], w2 = wl4[ch * 9 + 2];
    float4 w3 = wl4[ch * 9 + 3], w4 = wl4[ch * 9 + 4], w5 = wl4[ch * 9 + 5];
    float4 w6 = wl4[ch * 9 + 6], w7 = wl4[ch * 9 + 7], w8 = wl4[ch * 9 + 8];
    acc[0] = fmaf(w0.x, la, fmaf(w1.x, va, fmaf(w2.x, ga, acc[0])));
    acc[1] = fmaf(w0.y, la, fmaf(w1.y, va, fmaf(w2.y, ga, acc[1])));
    acc[2] = fmaf(w0.z, la, fmaf(w1.z, va, fmaf(w2.z, ga, acc[2])));
    acc[3] = fmaf(w0.w, la, fmaf(w1.w, va, fmaf(w2.w, ga, acc[3])));
    acc[0] = fmaf(w3.x, lb, fmaf(w4.x, vb, fmaf(w5.x, gb, acc[0])));
    acc[1] = fmaf(w3.y, lb, fmaf(w4.y, vb, fmaf(w5.y, gb, acc[1])));
    acc[2] = fmaf(w3.z, lb, fmaf(w4.z, vb, fmaf(w5.z, gb, acc[2])));
    acc[3] = fmaf(w3.w, lb, fmaf(w4.w, vb, fmaf(w5.w, gb, acc[3])));
    acc[0] = fmaf(w6.x, lc, fmaf(w7.x, vc, fmaf(w8.x, gc, acc[0])));
    acc[1] = fmaf(w6.y, lc, fmaf(w7.y, vc, fmaf(w8.y, gc, acc[1])));
    acc[2] = fmaf(w6.z, lc, fmaf(w7.z, vc, fmaf(w8.z, gc, acc[2])));
    acc[3] = fmaf(w6.w, lc, fmaf(w7.w, vc, fmaf(w8.w, gc, acc[3])));
  };
  __syncthreads();   // weights ready
#pragma unroll
  for (int i = 0; i < 16; ++i) tap9(c0 + i, ra[i], rb[i], rc[i]);
  if (wv == 3) {
    // ch 64: xx varies along px (zero-padded rows/cols like real channels)
    float xx = (float)px * (2.f / 63.f) - 1.f;
    tap9(64, maskm * xx, xx, maskp * xx);
    // ch 65: yy constant along px, varies by row
    float ya = maskm * ((float)rm * (2.f / 63.f) - 1.f);
    float yb = (float)row * (2.f / 63.f) - 1.f;
    float yc = maskp * ((float)rp * (2.f / 63.f) - 1.f);
    tap9(65, ya, yb, yc);
  }
#pragma unroll
  for (int oo = 0; oo < 4; ++oo) part[wv][oo][px] = acc[oo];
  __syncthreads();
  int oc = t >> 6;
  float s = (part[0][oc][px] + part[1][oc][px]) + (part[2][oc][px] + part[3][oc][px]);
  float cav = ws[CA_OFF + (src * 2 + b) * 64 + o0 + oc];
  outp[((size_t)(b * 64 + o0 + oc)) * N_ + (size_t)row * 64 + px] = s * cav;
}

// ---------------- K2: 1x1 projections; Q/K pre-split hi/lo, V hi-only transposed ----------------
__global__ __launch_bounds__(256) void k_proj(float* __restrict__ ws,
                                              const float* __restrict__ xqw, const float* __restrict__ xqb,
                                              const float* __restrict__ xkw, const float* __restrict__ xkb,
                                              const float* __restrict__ xvw, const float* __restrict__ xvb,
                                              const float* __restrict__ gqw, const float* __restrict__ gqb,
                                              const float* __restrict__ gkw, const float* __restrict__ gkb) {
  int blk = blockIdx.x;  // 5 * 2 * 64
  int pt = blk & 63; blk >>= 6;
  int b  = blk & 1;  blk >>= 1;
  int which = blk;
  size_t in_o;
  const float *wp, *bp;
  size_t hU = 0, lU = 0;
  if (which == 0)      { in_o = XG_OFF; wp = xqw; bp = xqb; hU = QXH_U; lU = QXL_U; }
  else if (which == 1) { in_o = XG_OFF; wp = xkw; bp = xkb; hU = KXH_U; lU = KXL_U; }
  else if (which == 2) { in_o = XG_OFF; wp = xvw; bp = xvb; }
  else if (which == 3) { in_o = GG_OFF; wp = gqw; bp = gqb; hU = QGH_U; lU = QGL_U; }
  else                 { in_o = GG_OFF; wp = gkw; bp = gkb; hU = KGH_U; lU = KGL_U; }

  __shared__ float tile[64 * 64];
  __shared__ float wl[64 * 65];
  __shared__ float bl[64];
  unsigned short* us = (unsigned short*)ws;
  int t = threadIdx.x;
  int pb = pt * 64;
  const float* in0 = ws + in_o + (size_t)b * CN + pb;
  for (int c0 = (t >> 6); c0 < 64; c0 += 4)
    tile[c0 * 64 + (t & 63)] = in0[(size_t)c0 * N_ + (t & 63)];
  for (int idx = t; idx < 4096; idx += 256)
    wl[(idx >> 6) * 65 + (idx & 63)] = wp[idx];
  if (t < 64) bl[t] = bp[t];
  __syncthreads();
  int o = t & 63, grp = t >> 6;
  const float* wr = &wl[o * 65];
  float acc[16];
  float bv = bl[o];
#pragma unroll
  for (int j = 0; j < 16; ++j) acc[j] = bv;
  for (int c = 0; c < 64; ++c) {
    float wv = wr[c];
    const float4* tb = reinterpret_cast<const float4*>(&tile[c * 64 + grp * 16]);
    float4 t0 = tb[0], t1 = tb[1], t2 = tb[2], t3 = tb[3];
    acc[0] = fmaf(wv, t0.x, acc[0]);   acc[1] = fmaf(wv, t0.y, acc[1]);
    acc[2] = fmaf(wv, t0.z, acc[2]);   acc[3] = fmaf(wv, t0.w, acc[3]);
    acc[4] = fmaf(wv, t1.x, acc[4]);   acc[5] = fmaf(wv, t1.y, acc[5]);
    acc[6] = fmaf(wv, t1.z, acc[6]);   acc[7] = fmaf(wv, t1.w, acc[7]);
    acc[8] = fmaf(wv, t2.x, acc[8]);   acc[9] = fmaf(wv, t2.y, acc[9]);
    acc[10] = fmaf(wv, t2.z, acc[10]); acc[11] = fmaf(wv, t2.w, acc[11]);
    acc[12] = fmaf(wv, t3.x, acc[12]); acc[13] = fmaf(wv, t3.y, acc[13]);
    acc[14] = fmaf(wv, t3.z, acc[14]); acc[15] = fmaf(wv, t3.w, acc[15]);
  }
  if (which != 2) {
#pragma unroll
    for (int j = 0; j < 16; ++j) {
      size_t idx = ((size_t)b * N_ + pb + grp * 16 + j) * 64 + o;
      unsigned short hi = b16(acc[j]);
      us[hU + idx] = hi;
      us[lU + idx] = b16(acc[j] - fromb16(hi));
    }
  } else {
    __syncthreads();
    float* ot = wl;
#pragma unroll
    for (int j = 0; j < 16; ++j) ot[o * 65 + grp * 16 + j] = acc[j];
    __syncthreads();
    int o2 = t >> 2;
#pragma unroll
    for (int e = 0; e < 4; ++e) {
      int px = (t & 3) * 16 + e * 4;
      u16x4 hv;
#pragma unroll
      for (int q = 0; q < 4; ++q) hv[q] = b16(ot[o2 * 65 + px + q]);
      size_t idx = ((size_t)(b * 64 + o2)) * N_ + pb + px;
      *reinterpret_cast<u16x4*>(&us[VXH_U + idx]) = hv;
    }
  }
}

// ---------------- K3: MFMA flash attention (R4 structure + V-direct + packed P) ----------------
__global__ __launch_bounds__(256) void k_attn(float* __restrict__ ws) {
  unsigned short* us = (unsigned short*)ws;
  int blk = blockIdx.x;
  int half = blk & 1; blk >>= 1;
  int qt = blk & 63;  blk >>= 6;
  int b  = blk & 1;   blk >>= 1;
  int at = blk;
  const unsigned short* QH = us + (at ? QGH_U : QXH_U);
  const unsigned short* QL = us + (at ? QGL_U : QXL_U);
  const unsigned short* KHg = us + (at ? KGH_U : KXH_U);
  const unsigned short* KLg = us + (at ? KGL_U : KXL_U);
  const unsigned short* VHg = us + VXH_U;
  float* Pg = ws + (at ? (half ? P1G_OFF : GG_OFF) : (half ? P1X_OFF : XG_OFF))
            + (size_t)b * CN + qt * 64;

  __shared__ unsigned short Kh[2][4096], Kl[2][4096], Ph[4096];   // 40 KB

  int t = threadIdx.x;
  int w = t >> 6, lane = t & 63, quad = lane >> 4, l15 = lane & 15;
  int swz = l15 & 7;

  short8 qh[2], ql[2];
  {
    size_t qbase = ((size_t)b * N_ + qt * 64 + 16 * w + l15) * 64;
#pragma unroll
    for (int ks = 0; ks < 2; ++ks) {
      qh[ks] = *reinterpret_cast<const short8*>(&QH[qbase + ks * 32 + quad * 8]);
      ql[ks] = *reinterpret_cast<const short8*>(&QL[qbase + ks * 32 + quad * 8]);
    }
  }

  short8 ones;
#pragma unroll
  for (int j = 0; j < 8; ++j) ones[j] = (short)0x3F80;  // bf16 1.0

  int mt0 = half * 32, mt1 = half * 32 + 32;

  u16x8 rkh[2], rkl[2];
  size_t ko = ((size_t)b * N_ + (size_t)mt0 * 64 + (t >> 3)) * 64 + (size_t)(t & 7) * 8;
  auto prefetchK = [&]() {
    rkh[0] = *reinterpret_cast<const u16x8*>(&KHg[ko]);
    rkl[0] = *reinterpret_cast<const u16x8*>(&KLg[ko]);
    rkh[1] = *reinterpret_cast<const u16x8*>(&KHg[ko + 2048]);
    rkl[1] = *reinterpret_cast<const u16x8*>(&KLg[ko + 2048]);
    ko += 4096;
  };
  int wr0 = t >> 3, wch = t & 7;
  int woff = wr0 * 64 + ((wch ^ (wr0 & 7)) << 3);
  auto writebufK = [&](int par) {
    *reinterpret_cast<u16x8*>(&Kh[par][woff]) = rkh[0];
    *reinterpret_cast<u16x8*>(&Kl[par][woff]) = rkl[0];
    *reinterpret_cast<u16x8*>(&Kh[par][woff + 2048]) = rkh[1];
    *reinterpret_cast<u16x8*>(&Kl[par][woff + 2048]) = rkl[1];
  };

  // V straight from global: lane needs V[ch=cs*16+l15][mt*64 + ks*32 + quad*8 ..+7]
  size_t vb = ((size_t)(b * 64 + l15)) * N_ + (size_t)mt0 * 64 + quad * 8;

  f32x4 Oa[4] = {{0.f, 0.f, 0.f, 0.f}, {0.f, 0.f, 0.f, 0.f},
                 {0.f, 0.f, 0.f, 0.f}, {0.f, 0.f, 0.f, 0.f}};
  f32x4 La = {0.f, 0.f, 0.f, 0.f};   // L via ones-row MFMA (rows identical)
  float M = -1e30f;                  // per-lane: pixel n = 16w + l15 (quad-uniform)

  int phb = (16 * w + l15) * 64;
  int mh = quad >> 1, mlw = (quad & 1) * 4;

  prefetchK();
  writebufK(0);
  __syncthreads();
  for (int mt = mt0; mt < mt1; ++mt) {
    int pb = (mt - mt0) & 1;
    // V ks=0 loads for THIS tile: retire under the QK phase
    u16x8 rvA[4];
#pragma unroll
    for (int cs = 0; cs < 4; ++cs)
      rvA[cs] = *reinterpret_cast<const u16x8*>(&VHg[vb + (size_t)cs * 16 * N_]);
    if (mt + 1 < mt1) prefetchK();   // K for next tile

    // S^T[m][n]: m = ms*16 + quad*4 + reg, n = 16w + l15 (swapped operands)
    f32x4 S[4];
    __builtin_amdgcn_s_setprio(1);
#pragma unroll
    for (int ms = 0; ms < 4; ++ms) {
      f32x4 a0 = {0.f, 0.f, 0.f, 0.f}, a1 = {0.f, 0.f, 0.f, 0.f};
      int row = ms * 16 + l15;
#pragma unroll
      for (int ks = 0; ks < 2; ++ks) {
        int off = row * 64 + (((ks * 4 + quad) ^ swz) << 3);
        short8 khf = *reinterpret_cast<const short8*>(&Kh[pb][off]);
        short8 klf = *reinterpret_cast<const short8*>(&Kl[pb][off]);
        f32x4& a = ks ? a1 : a0;
        a = MFMA_BF16(khf, ql[ks], a, 0, 0, 0);
        a = MFMA_BF16(klf, qh[ks], a, 0, 0, 0);
        a = MFMA_BF16(khf, qh[ks], a, 0, 0, 0);
      }
      S[ms] = a0 + a1;
    }
    __builtin_amdgcn_s_setprio(0);

    // V ks=1 loads: issued here, covered by softmax + PV ks=0
    u16x8 rvB[4];
#pragma unroll
    for (int cs = 0; cs < 4; ++cs)
      rvB[cs] = *reinterpret_cast<const u16x8*>(&VHg[vb + (size_t)cs * 16 * N_ + 32]);
    vb += 64;

    // in-lane max (max3-shaped) + 2-step cross-quad butterfly
    float t0 = fmaxf(fmaxf(S[0][0], S[0][1]), S[0][2]);
    float t1 = fmaxf(fmaxf(S[0][3], S[1][0]), S[1][1]);
    float t2 = fmaxf(fmaxf(S[1][2], S[1][3]), S[2][0]);
    float t3 = fmaxf(fmaxf(S[2][1], S[2][2]), S[2][3]);
    float t4 = fmaxf(fmaxf(S[3][0], S[3][1]), S[3][2]);
    float t5 = fmaxf(fmaxf(t0, t1), t2);
    float t6 = fmaxf(fmaxf(t3, t4), S[3][3]);
    float tm = fmaxf(t5, t6);
    tm = fmaxf(tm, __shfl_xor(tm, 16, 64));
    tm = fmaxf(tm, __shfl_xor(tm, 32, 64));
    float mn = fmaxf(M, tm);
    float al = __expf(M - mn);
    M = mn;
#pragma unroll
    for (int ms = 0; ms < 4; ++ms) {
      int goff = phb + ((((ms << 1) + mh) ^ swz) << 3) + mlw;
      unsigned lo = (unsigned)b16(__expf(S[ms][0] - mn)) |
                    ((unsigned)b16(__expf(S[ms][1] - mn)) << 16);
      unsigned hi = (unsigned)b16(__expf(S[ms][2] - mn)) |
                    ((unsigned)b16(__expf(S[ms][3] - mn)) << 16);
      uint2 pk; pk.x = lo; pk.y = hi;
      *reinterpret_cast<uint2*>(&Ph[goff]) = pk;   // 8B store, wave-private rows
    }
#pragma unroll
    for (int cs = 0; cs < 4; ++cs) {
      Oa[cs][0] *= al; Oa[cs][1] *= al; Oa[cs][2] *= al; Oa[cs][3] *= al;
    }
    La[0] *= al;

    // O^T += V^T P^T (V from regs): 10 MFMAs incl. 2 ones-row for L
    __builtin_amdgcn_s_setprio(1);
    {
      int poff = phb + ((quad ^ swz) << 3);
      short8 phf = *reinterpret_cast<const short8*>(&Ph[poff]);
      La = MFMA_BF16(ones, phf, La, 0, 0, 0);
#pragma unroll
      for (int cs = 0; cs < 4; ++cs)
        Oa[cs] = MFMA_BF16((short8)rvA[cs], phf, Oa[cs], 0, 0, 0);
    }
    {
      int poff = phb + (((4 + quad) ^ swz) << 3);
      short8 phf = *reinterpret_cast<const short8*>(&Ph[poff]);
      La = MFMA_BF16(ones, phf, La, 0, 0, 0);
#pragma unroll
      for (int cs = 0; cs < 4; ++cs)
        Oa[cs] = MFMA_BF16((short8)rvB[cs], phf, Oa[cs], 0, 0, 0);
    }
    __builtin_amdgcn_s_setprio(0);

    if (mt + 1 < mt1) writebufK(pb ^ 1);  // fenced by previous iteration's barrier
    __syncthreads();
  }

#pragma unroll
  for (int cs = 0; cs < 4; ++cs) {
#pragma unroll
    for (int r = 0; r < 4; ++r) {
      int c = cs * 16 + quad * 4 + r;
      Pg[(size_t)c * N_ + 16 * w + l15] = Oa[cs][r];
    }
  }
  if (quad == 0) {
    int mlb = ((at * 2 + half) * 2 + b) * 4096 + qt * 64 + 16 * w + l15;
    ws[ML_OFF + mlb] = M;
    ws[MLL_OFF + mlb] = La[0];   // La col = pixel 16w+l15, rows identical
  }
}

// ---------------- K4: merge halves + combine ----------------
__global__ __launch_bounds__(256) void k_merge(float* __restrict__ ws,
                                               const float* __restrict__ gm_p,
                                               const float* __restrict__ al_p) {
  size_t i4 = (size_t)blockIdx.x * 256 + threadIdx.x;
  size_t i = i4 * 4;
  int n = (int)(i & 4095);
  int b = (int)(i >> 18);
  float gm = gm_p[0], al = al_p[0];
  float4 p0x = *reinterpret_cast<const float4*>(ws + XG_OFF + i);
  float4 p1x = *reinterpret_cast<const float4*>(ws + P1X_OFF + i);
  float4 p0g = *reinterpret_cast<const float4*>(ws + GG_OFF + i);
  float4 p1g = *reinterpret_cast<const float4*>(ws + P1G_OFF + i);
  float4 M0x = *reinterpret_cast<const float4*>(ws + ML_OFF  + (0 + b) * 4096 + n);
  float4 L0x = *reinterpret_cast<const float4*>(ws + MLL_OFF + (0 + b) * 4096 + n);
  float4 M1x = *reinterpret_cast<const float4*>(ws + ML_OFF  + (2 + b) * 4096 + n);
  float4 L1x = *reinterpret_cast<const float4*>(ws + MLL_OFF + (2 + b) * 4096 + n);
  float4 M0g = *reinterpret_cast<const float4*>(ws + ML_OFF  + (4 + b) * 4096 + n);
  float4 L0g = *reinterpret_cast<const float4*>(ws + MLL_OFF + (4 + b) * 4096 + n);
  float4 M1g = *reinterpret_cast<const float4*>(ws + ML_OFF  + (6 + b) * 4096 + n);
  float4 L1g = *reinterpret_cast<const float4*>(ws + MLL_OFF + (6 + b) * 4096 + n);
  const float* p0xv = (const float*)&p0x; const float* p1xv = (const float*)&p1x;
  const float* p0gv = (const float*)&p0g; const float* p1gv = (const float*)&p1g;
  const float* m0xv = (const float*)&M0x; const float* l0xv = (const float*)&L0x;
  const float* m1xv = (const float*)&M1x; const float* l1xv = (const float*)&L1x;
  const float* m0gv = (const float*)&M0g; const float* l0gv = (const float*)&L0g;
  const float* m1gv = (const float*)&M1g; const float* l1gv = (const float*)&L1g;
  float4 go, ob;
  float* gov = (float*)&go; float* obv = (float*)&ob;
#pragma unroll
  for (int l = 0; l < 4; ++l) {
    float mx = fmaxf(m0xv[l], m1xv[l]);
    float w0 = __expf(m0xv[l] - mx), w1 = __expf(m1xv[l] - mx);
    float xc = (p0xv[l] * w0 + p1xv[l] * w1) / (l0xv[l] * w0 + l1xv[l] * w1);
    float mg = fmaxf(m0gv[l], m1gv[l]);
    float v0 = __expf(m0gv[l] - mg), v1 = __expf(m1gv[l] - mg);
    float gc = (p0gv[l] * v0 + p1gv[l] * v1) / (l0gv[l] * v0 + l1gv[l] * v1);
    gov[l] = gc;
    obv[l] = gm * xc + al * gc;
  }
  *reinterpret_cast<float4*>(ws + GG_OFF + i) = go;  // GO
  *reinterpret_cast<float4*>(ws + QX_OFF + i) = ob;  // OB
}

// ---------------- K5: u = leaky(conv3x3(leaky(out), c1)), channel-split ----------------
__global__ __launch_bounds__(256) void k_conv1(float* __restrict__ ws,
                                               const float* __restrict__ c1w,
                                               const float* __restrict__ c1b) {
  int blk = blockIdx.x;  // 2048 = b*1024 + og*64 + row
  int row = blk & 63; blk >>= 6;
  int og  = blk & 15; blk >>= 4;
  int b   = blk;
  int o0 = og * 4;
  __shared__ __align__(16) float4 wl4[576];
  __shared__ float part[4][4][64];
  int t = threadIdx.x;
  int wv = t >> 6, px = t & 63;
  {
    float* wlf = (float*)wl4;
    for (int idx = t; idx < 2304; idx += 256)
      wlf[idx] = c1w[(size_t)(o0 + (idx & 3)) * 576 + (idx >> 2)];
  }
  int rm = row - 1, rp = row + 1;
  int rmc = rm < 0 ? 0 : rm, rpc = rp > 63 ? 63 : rp;
  float maskm = rm < 0 ? 0.f : 1.f, maskp = rp > 63 ? 0.f : 1.f;
  int c0 = wv * 16;
  const float* base = ws + OB_OFF + (size_t)b * CN + (size_t)c0 * N_ + px;
  float ra[16], rb[16], rc[16];
#pragma unroll
  for (int i = 0; i < 16; ++i) {
    ra[i] = leaky(base[(size_t)i * N_ + (size_t)rmc * 64]) * maskm;
    rb[i] = leaky(base[(size_t)i * N_ + (size_t)row * 64]);
    rc[i] = leaky(base[(size_t)i * N_ + (size_t)rpc * 64]) * maskp;
  }
  float acc[4] = {};
  auto tap9 = [&](int ch, float va, float vb, float vc) {
    float la = __shfl_up(va, 1, 64);   if (px == 0)  la = 0.f;
    float ga = __shfl_down(va, 1, 64); if (px == 63) ga = 0.f;
    float lb = __shfl_up(vb, 1, 64);   if (px == 0)  lb = 0.f;
    float gb = __shfl_down(vb, 1, 64); if (px == 63) gb = 0.f;
    float lc = __shfl_up(vc, 1, 64);   if (px == 0)  lc = 0.f;
    float gc = __shfl_down(vc, 1, 64); if (px == 63) gc = 0.f;
    float4 w0 = wl4[ch * 9 + 0], w1 = wl4[ch * 9 + 1], w2 = wl4[ch * 9 + 2];
    float4 w3 = wl4[ch * 9 + 3], w4 = wl4[ch * 9 + 4], w5 = wl4[ch * 9 + 5];
    float4 w6 = wl4[ch * 9 + 6], w7 = wl4[ch * 9 + 7], w8 = wl4[ch * 9 + 8];
    acc[0] = fmaf(w0.x, la, fmaf(w1.x, va, fmaf(w2.x, ga, acc[0])));
    acc[1] = fmaf(w0.y, la, fmaf(w1.y, va, fmaf(w2.y, ga, acc[1])));
    acc[2] = fmaf(w0.z, la, fmaf(w1.z, va, fmaf(w2.z, ga, acc[2])));
    acc[3] = fmaf(w0.w, la, fmaf(w1.w, va, fmaf(w2.w, ga, acc[3])));
    acc[0] = fmaf(w3.x, lb, fmaf(w4.x, vb, fmaf(w5.x, gb, acc[0])));
    acc[1] = fmaf(w3.y, lb, fmaf(w4.y, vb, fmaf(w5.y, gb, acc[1])));
    acc[2] = fmaf(w3.z, lb, fmaf(w4.z, vb, fmaf(w5.z, gb, acc[2])));
    acc[3] = fmaf(w3.w, lb, fmaf(w4.w, vb, fmaf(w5.w, gb, acc[3])));
    acc[0] = fmaf(w6.x, lc, fmaf(w7.x, vc, fmaf(w8.x, gc, acc[0])));
    acc[1] = fmaf(w6.y, lc, fmaf(w7.y, vc, fmaf(w8.y, gc, acc[1])));
    acc[2] = fmaf(w6.z, lc, fmaf(w7.z, vc, fmaf(w8.z, gc, acc[2])));
    acc[3] = fmaf(w6.w, lc, fmaf(w7.w, vc, fmaf(w8.w, gc, acc[3])));
  };
  __syncthreads();
#pragma unroll
  for (int i = 0; i < 16; ++i) tap9(c0 + i, ra[i], rb[i], rc[i]);
#pragma unroll
  for (int oo = 0; oo < 4; ++oo) part[wv][oo][px] = acc[oo];
  __syncthreads();
  int oc = t >> 6;
  float s = (part[0][oc][px] + part[1][oc][px]) + (part[2][oc][px] + part[3][oc][px]);
  float* ub = ws + UB_OFF + (size_t)b * CN;
  ub[(size_t)(o0 + oc) * N_ + (size_t)row * 64 + px] = leaky(s + c1b[o0 + oc]);
}

// ---------------- K6: final, channel-split + fused sc dot ----------------
__global__ __launch_bounds__(256) void k_final(const float* __restrict__ ws,
                                               const float* __restrict__ c2w,
                                               const float* __restrict__ c2b,
                                               const float* __restrict__ scw,
                                               const float* __restrict__ scb,
                                               float* __restrict__ out) {
  int blk = blockIdx.x;  // 2048 = b*1024 + og*64 + row
  int row = blk & 63; blk >>= 6;
  int og  = blk & 15; blk >>= 4;
  int b   = blk;
  int o0 = og * 4;
  __shared__ __align__(16) float4 wl4[576];
  __shared__ __align__(16) float4 scl4[64];
  __shared__ float part[4][4][64];
  __shared__ float part2[4][4][64];
  int t = threadIdx.x;
  int wv = t >> 6, px = t & 63;
  {
    float* wlf = (float*)wl4;
    for (int idx = t; idx < 2304; idx += 256)
      wlf[idx] = c2w[(size_t)(o0 + (idx & 3)) * 576 + (idx >> 2)];
    float* sclf = (float*)scl4;
    if (t < 256) {
      int idx = t;
      sclf[idx] = scw[(size_t)(o0 + (idx & 3)) * 64 + (idx >> 2)];
    }
  }
  int rm = row - 1, rp = row + 1;
  int rmc = rm < 0 ? 0 : rm, rpc = rp > 63 ? 63 : rp;
  float maskm = rm < 0 ? 0.f : 1.f, maskp = rp > 63 ? 0.f : 1.f;
  int c0 = wv * 16;
  const float* base = ws + UB_OFF + (size_t)b * CN + (size_t)c0 * N_ + px;
  const float* obb  = ws + OB_OFF + (size_t)b * CN + (size_t)c0 * N_ + (size_t)row * 64 + px;
  float ra[16], rb[16], rc[16], ob[16];
#pragma unroll
  for (int i = 0; i < 16; ++i) {
    ra[i] = base[(size_t)i * N_ + (size_t)rmc * 64] * maskm;
    rb[i] = base[(size_t)i * N_ + (size_t)row * 64];
    rc[i] = base[(size_t)i * N_ + (size_t)rpc * 64] * maskp;
    ob[i] = obb[(size_t)i * N_];
  }
  float acc[4] = {};
  float scp[4] = {};
  auto tap9 = [&](int ch, float va, float vb, float vc) {
    float la = __shfl_up(va, 1, 64);   if (px == 0)  la = 0.f;
    float ga = __shfl_down(va, 1, 64); if (px == 63) ga = 0.f;
    float lb = __shfl_up(vb, 1, 64);   if (px == 0)  lb = 0.f;
    float gb = __shfl_down(vb, 1, 64); if (px == 63) gb = 0.f;
    float lc = __shfl_up(vc, 1, 64);   if (px == 0)  lc = 0.f;
    float gc = __shfl_down(vc, 1, 64); if (px == 63) gc = 0.f;
    float4 w0 = wl4[ch * 9 + 0], w1 = wl4[ch * 9 + 1], w2 = wl4[ch * 9 + 2];
    float4 w3 = wl4[ch * 9 + 3], w4 = wl4[ch * 9 + 4], w5 = wl4[ch * 9 + 5];
    float4 w6 = wl4[ch * 9 + 6], w7 = wl4[ch * 9 + 7], w8 = wl4[ch * 9 + 8];
    acc[0] = fmaf(w0.x, la, fmaf(w1.x, va, fmaf(w2.x, ga, acc[0])));
    acc[1] = fmaf(w0.y, la, fmaf(w1.y, va, fmaf(w2.y, ga, acc[1])));
    acc[2] = fmaf(w0.z, la, fmaf(w1.z, va, fmaf(w2.z, ga, acc[2])));
    acc[3] = fmaf(w0.w, la, fmaf(w1.w, va, fmaf(w2.w, ga, acc[3])));
    acc[0] = fmaf(w3.x, lb, fmaf(w4.x, vb, fmaf(w5.x, gb, acc[0])));
    acc[1] = fmaf(w3.y, lb, fmaf(w4.y, vb, fmaf(w5.y, gb, acc[1])));
    acc[2] = fmaf(w3.z, lb, fmaf(w4.z, vb, fmaf(w5.z, gb, acc[2])));
    acc[3] = fmaf(w3.w, lb, fmaf(w4.w, vb, fmaf(w5.w, gb, acc[3])));
    acc[0] = fmaf(w6.x, lc, fmaf(w7.x, vc, fmaf(w8.x, gc, acc[0])));
    acc[1] = fmaf(w6.y, lc, fmaf(w7.y, vc, fmaf(w8.y, gc, acc[1])));
    acc[2] = fmaf(w6.z, lc, fmaf(w7.z, vc, fmaf(w8.z, gc, acc[2])));
    acc[3] = fmaf(w6.w, lc, fmaf(w7.w, vc, fmaf(w8.w, gc, acc[3])));
  };
  __syncthreads();
#pragma unroll
  for (int i = 0; i < 16; ++i) {
    tap9(c0 + i, ra[i], rb[i], rc[i]);
    float4 s4 = scl4[c0 + i];
    scp[0] = fmaf(s4.x, ob[i], scp[0]);
    scp[1] = fmaf(s4.y, ob[i], scp[1]);
    scp[2] = fmaf(s4.z, ob[i], scp[2]);
    scp[3] = fmaf(s4.w, ob[i], scp[3]);
  }
#pragma unroll
  for (int oo = 0; oo < 4; ++oo) {
    part[wv][oo][px] = acc[oo];
    part2[wv][oo][px] = scp[oo];
  }
  __syncthreads();
  int oc = t >> 6;
  float s  = (part[0][oc][px] + part[1][oc][px]) + (part[2][oc][px] + part[3][oc][px]);
  float sc = (part2[0][oc][px] + part2[1][oc][px]) + (part2[2][oc][px] + part2[3][oc][px]);
  const float* go = ws + GO_OFF + (size_t)b * CN;
  size_t pix = (size_t)row * 64 + px;
  float gvv = go[(size_t)(o0 + oc) * N_ + pix];
  out[(size_t)b * CN + (size_t)(o0 + oc) * N_ + pix] =
      (s + c2b[o0 + oc]) + (sc + scb[o0 + oc]) * gvv;
}

extern "C" void kernel_launch(void* const* d_in, const int* in_sizes, int n_in,
                              void* d_out, int out_size, void* d_ws, size_t ws_size,
                              hipStream_t stream) {
  const float* x     = (const float*)d_in[0];
  const float* guide = (const float*)d_in[1];
  const float* lin_w = (const float*)d_in[2];
  const float* lin_b = (const float*)d_in[3];
  const float* cw    = (const float*)d_in[4];
  const float* xq_w  = (const float*)d_in[5];
  const float* xq_b  = (const float*)d_in[6];
  const float* xk_w  = (const float*)d_in[7];
  const float* xk_b  = (const float*)d_in[8];
  const float* xv_w  = (const float*)d_in[9];
  const float* xv_b  = (const float*)d_in[10];
  const float* gq_w  = (const float*)d_in[11];
  const float* gq_b  = (const float*)d_in[12];
  const float* gk_w  = (const float*)d_in[13];
  const float* gk_b  = (const float*)d_in[14];
  const float* gamma = (const float*)d_in[15];
  const float* alpha = (const float*)d_in[16];
  const float* c1_w  = (const float*)d_in[17];
  const float* c1_b  = (const float*)d_in[18];
  const float* c2_w  = (const float*)d_in[19];
  const float* c2_b  = (const float*)d_in[20];
  const float* sc_w  = (const float*)d_in[21];
  const float* sc_b  = (const float*)d_in[22];
  float* out = (float*)d_out;
  float* ws = (float*)d_ws;

  k_ca<<<256, 64, 0, stream>>>(x, guide, lin_w, lin_b, ws);
  k_coordconv<<<4096, 256, 0, stream>>>(x, guide, cw, ws);
  k_proj<<<640, 256, 0, stream>>>(ws, xq_w, xq_b, xk_w, xk_b, xv_w, xv_b,
                                  gq_w, gq_b, gk_w, gk_b);
  k_attn<<<512, 256, 0, stream>>>(ws);
  k_merge<<<512, 256, 0, stream>>>(ws, gamma, alpha);
  k_conv1<<<2048, 256, 0, stream>>>(ws, c1_w, c1_b);
  k_final<<<2048, 256, 0, stream>>>(ws, c2_w, c2_b, sc_w, sc_b, out);
}